// Round 2
// baseline (1746.031 us; speedup 1.0000x reference)
//
#include <hip/hip_runtime.h>

typedef __bf16 bf16x8 __attribute__((ext_vector_type(8)));
typedef float f32x4 __attribute__((ext_vector_type(4)));
typedef unsigned short us8 __attribute__((ext_vector_type(8)));

typedef __attribute__((address_space(3))) void lds_void_t;
typedef const __attribute__((address_space(1))) void gbl_void_t;

__device__ __forceinline__ unsigned short f2bf(float f) {
    unsigned u = __builtin_bit_cast(unsigned, f);
    u += 0x7FFFu + ((u >> 16) & 1u);   // round-to-nearest-even
    return (unsigned short)(u >> 16);
}
__device__ __forceinline__ float bf2f(unsigned short h) {
    unsigned u = ((unsigned)h) << 16;
    return __builtin_bit_cast(float, u);
}

// ---------------- diagnostic: reveal ws_size via absmax if workspace too small ----
__global__ void report_ws(float* out, float v) { out[0] = v; }

// ---------------- f32 -> bf16 cast (vectorized) ----------------
__global__ __launch_bounds__(256) void cast_bf16(
    const float* __restrict__ src, unsigned short* __restrict__ dst, size_t n8)
{
    size_t i = (size_t)blockIdx.x * 256 + threadIdx.x;
    if (i >= n8) return;
    const float4* s = (const float4*)src + i * 2;
    float4 a = s[0], b = s[1];
    us8 o;
    o[0] = f2bf(a.x); o[1] = f2bf(a.y); o[2] = f2bf(a.z); o[3] = f2bf(a.w);
    o[4] = f2bf(b.x); o[5] = f2bf(b.y); o[6] = f2bf(b.z); o[7] = f2bf(b.w);
    *((us8*)dst + i) = o;
}

// ---------------- bf16 GEMM: Y = A @ W^T + bias (m97 structure) ----------------
// A [M,K] bf16 row-major, W [N,K] bf16 row-major, Y [M,N] bf16.
// 128x128 tile, BK=64, 256 threads (4 waves, 2x2), 16x16x32 MFMA, 4x4 frags/wave.
__global__ __launch_bounds__(256) void gemm_bt(
    const unsigned short* __restrict__ A,
    const unsigned short* __restrict__ W,
    const float* __restrict__ bias,
    unsigned short* __restrict__ Y,
    int M, int N, int K)
{
    __shared__ unsigned short As[128][64];
    __shared__ unsigned short Ws[128][64];

    const int nbx = N >> 7;
    const int nwg = gridDim.x;
    const int cpx = nwg >> 3;                 // nwg % 8 == 0 guaranteed by launch
    const int bid = blockIdx.x;
    const int swz = (bid & 7) * cpx + (bid >> 3);   // bijective XCD swizzle
    const int bm = swz / nbx;
    const int bn = swz % nbx;

    const int t    = threadIdx.x;
    const int wv   = t >> 6;
    const int lane = t & 63;
    const int wr   = (wv >> 1) << 6;          // wave row offset (0/64)
    const int wc   = (wv & 1) << 6;           // wave col offset (0/64)
    const int fr   = lane & 15;
    const int fq   = lane >> 4;

    // staging map: thread t loads 16B -> LDS linear byte offset t*16 within chunk
    const int srow = t >> 3;                  // 0..31 (row within 32-row chunk)
    const int scol = (t & 7) << 3;            // k element offset (0..56)
    const unsigned ldsOff = (unsigned)wv << 10;  // wave-uniform base; +lane*16 by HW

    const size_t baseA = (size_t)(bm << 7) * K;
    const size_t baseW = (size_t)(bn << 7) * K;

    f32x4 acc[4][4];
#pragma unroll
    for (int m = 0; m < 4; ++m)
#pragma unroll
        for (int n = 0; n < 4; ++n)
            acc[m][n] = (f32x4){0.f, 0.f, 0.f, 0.f};

    for (int k0 = 0; k0 < K; k0 += 64) {
#pragma unroll
        for (int c = 0; c < 4; ++c) {
            const unsigned short* ga = A + baseA + (size_t)(c * 32 + srow) * K + (k0 + scol);
            const unsigned short* gw = W + baseW + (size_t)(c * 32 + srow) * K + (k0 + scol);
            __builtin_amdgcn_global_load_lds((gbl_void_t*)ga,
                (lds_void_t*)((char*)&As[0][0] + c * 4096 + ldsOff), 16, 0, 0);
            __builtin_amdgcn_global_load_lds((gbl_void_t*)gw,
                (lds_void_t*)((char*)&Ws[0][0] + c * 4096 + ldsOff), 16, 0, 0);
        }
        __syncthreads();
#pragma unroll
        for (int kk = 0; kk < 2; ++kk) {
            bf16x8 af[4], wf[4];
#pragma unroll
            for (int m = 0; m < 4; ++m)
                af[m] = *(const bf16x8*)&As[wr + m * 16 + fr][kk * 32 + fq * 8];
#pragma unroll
            for (int n = 0; n < 4; ++n)
                wf[n] = *(const bf16x8*)&Ws[wc + n * 16 + fr][kk * 32 + fq * 8];
#pragma unroll
            for (int m = 0; m < 4; ++m)
#pragma unroll
                for (int n = 0; n < 4; ++n)
                    acc[m][n] = __builtin_amdgcn_mfma_f32_16x16x32_bf16(
                        af[m], wf[n], acc[m][n], 0, 0, 0);
        }
        __syncthreads();
    }

    // epilogue: +bias, write bf16. C/D map: col = lane&15, row = (lane>>4)*4 + r
#pragma unroll
    for (int n = 0; n < 4; ++n) {
        const int col = (bn << 7) + wc + n * 16 + fr;
        const float bv = bias[col];
#pragma unroll
        for (int m = 0; m < 4; ++m) {
            const int row0 = (bm << 7) + wr + m * 16 + fq * 4;
#pragma unroll
            for (int r = 0; r < 4; ++r)
                Y[(size_t)(row0 + r) * N + col] = f2bf(acc[m][n][r] + bv);
        }
    }
}

// ---------------- BN column stats, stage 1: deterministic partials ----------------
// grid (N/256, CH); each thread owns one column over rowsPer rows.
__global__ __launch_bounds__(256) void col_stats1(
    const unsigned short* __restrict__ Y, float* __restrict__ psum,
    float* __restrict__ psumsq, int N, int rowsPer)
{
    const int col = blockIdx.x * 256 + threadIdx.x;
    const int r0  = blockIdx.y * rowsPer;
    const unsigned short* p = Y + (size_t)r0 * N + col;
    float s = 0.f, ss = 0.f;
    for (int r = 0; r < rowsPer; ++r) {
        float v = bf2f(p[(size_t)r * N]);
        s += v; ss += v * v;
    }
    psum  [(size_t)blockIdx.y * N + col] = s;
    psumsq[(size_t)blockIdx.y * N + col] = ss;
}

// ---------------- BN stats, stage 2: finalize scale/shift ----------------
__global__ __launch_bounds__(256) void col_stats2(
    const float* __restrict__ psum, const float* __restrict__ psumsq,
    const float* __restrict__ g, const float* __restrict__ be,
    float* __restrict__ scale, float* __restrict__ shift,
    int N, int CH, float invM)
{
    const int col = blockIdx.x * 256 + threadIdx.x;
    float s = 0.f, ss = 0.f;
    for (int c = 0; c < CH; ++c) {
        s  += psum  [(size_t)c * N + col];
        ss += psumsq[(size_t)c * N + col];
    }
    float mu  = s * invM;
    float var = ss * invM - mu * mu;   // biased var, matches torch BN normalization
    float a = g[col] * rsqrtf(var + 1e-5f);
    scale[col] = a;
    shift[col] = be[col] - mu * a;
}

// ---------------- fused normalize + LeakyReLU(0.5), in place ----------------
__global__ __launch_bounds__(256) void norm_leaky(
    unsigned short* __restrict__ Y, const float* __restrict__ scale,
    const float* __restrict__ shift, int N, size_t n8)
{
    size_t i = (size_t)blockIdx.x * 256 + threadIdx.x;
    if (i >= n8) return;
    us8 v = *((const us8*)Y + i);
    const int col0 = (int)((i * 8) % (size_t)N);
    us8 o;
#pragma unroll
    for (int j = 0; j < 8; ++j) {
        float x = bf2f(v[j]) * scale[col0 + j] + shift[col0 + j];
        x = (x >= 0.f) ? x : 0.5f * x;
        o[j] = f2bf(x);
    }
    *((us8*)Y + i) = o;
}

// ---------------- final matvec: out[i] = X[i,:] . wout + bout ----------------
__global__ __launch_bounds__(256) void matvec_out(
    const unsigned short* __restrict__ X, const float* __restrict__ wvec,
    const float* __restrict__ bout, float* __restrict__ out, int Kd)
{
    const int row  = blockIdx.x * 4 + (threadIdx.x >> 6);
    const int lane = threadIdx.x & 63;
    const unsigned short* xr = X + (size_t)row * Kd;
    float s = 0.f;
    for (int j = lane * 8; j < Kd; j += 512) {
        us8 x = *(const us8*)(xr + j);
#pragma unroll
        for (int e = 0; e < 8; ++e) s += bf2f(x[e]) * wvec[j + e];
    }
#pragma unroll
    for (int off = 32; off > 0; off >>= 1) s += __shfl_down(s, off);
    if (lane == 0) out[row] = s + bout[0];
}

extern "C" void kernel_launch(void* const* d_in, const int* in_sizes, int n_in,
                              void* d_out, int out_size, void* d_ws, size_t ws_size,
                              hipStream_t stream)
{
    const float* x    = (const float*)d_in[0];
    const float* w1   = (const float*)d_in[1];
    const float* b1   = (const float*)d_in[2];
    const float* g1   = (const float*)d_in[3];
    const float* be1  = (const float*)d_in[4];
    const float* w2   = (const float*)d_in[5];
    const float* b2   = (const float*)d_in[6];
    const float* g2   = (const float*)d_in[7];
    const float* be2  = (const float*)d_in[8];
    const float* w3   = (const float*)d_in[9];
    const float* b3   = (const float*)d_in[10];
    const float* g3   = (const float*)d_in[11];
    const float* be3  = (const float*)d_in[12];
    const float* wout = (const float*)d_in[13];
    const float* bout = (const float*)d_in[14];
    float* out = (float*)d_out;

    const int B = 32768, D = 512, H1 = 2048, H2 = 2048, H3 = 1024;
    const int CH = 128;                 // row chunks for stats
    const int rowsPer = B / CH;         // 256
    const int RCH = 8192;               // row chunk for in-place GEMM (4 chunks)

    char* ws = (char*)d_ws;
    size_t off = 0;
    auto alloc = [&](size_t bytes) -> char* {
        char* p = ws + off;
        off += (bytes + 255) & ~(size_t)255;
        return p;
    };
    unsigned short* bufA    = (unsigned short*)alloc((size_t)B * H1 * 2);      // 134.2 MB
    unsigned short* scratch = (unsigned short*)alloc((size_t)RCH * H1 * 2);    //  33.6 MB
    unsigned short* W1b     = (unsigned short*)alloc((size_t)H1 * D * 2);      //   2.1 MB
    unsigned short* W2b     = (unsigned short*)alloc((size_t)H2 * H1 * 2);     //   8.4 MB
    unsigned short* W3b     = (unsigned short*)alloc((size_t)H3 * H2 * 2);     //   4.2 MB
    float* psum   = (float*)alloc((size_t)CH * H1 * 4);                        //   1.0 MB
    float* psumsq = (float*)alloc((size_t)CH * H1 * 4);                        //   1.0 MB
    float* scale  = (float*)alloc((size_t)H1 * 4);
    float* shift  = (float*)alloc((size_t)H1 * 4);

    if (off > ws_size) {                // workspace too small: report its size via absmax
        report_ws<<<1, 1, 0, stream>>>(out, (float)ws_size);
        return;
    }

    // --- input casts to bf16 (x goes into scratch, used only by GEMM1) ---
    {
        size_t n8;
        n8 = (size_t)B * D / 8;   cast_bf16<<<(unsigned)((n8 + 255) / 256), 256, 0, stream>>>(x,  scratch, n8);
        n8 = (size_t)H1 * D / 8;  cast_bf16<<<(unsigned)((n8 + 255) / 256), 256, 0, stream>>>(w1, W1b, n8);
        n8 = (size_t)H2 * H1 / 8; cast_bf16<<<(unsigned)((n8 + 255) / 256), 256, 0, stream>>>(w2, W2b, n8);
        n8 = (size_t)H3 * H2 / 8; cast_bf16<<<(unsigned)((n8 + 255) / 256), 256, 0, stream>>>(w3, W3b, n8);
    }

    const float invB = 1.0f / (float)B;

    // --- layer 1: [B,512] x [2048,512]^T -> bufA ---
    gemm_bt<<<(B / 128) * (H1 / 128), 256, 0, stream>>>(scratch, W1b, b1, bufA, B, H1, D);
    col_stats1<<<dim3(H1 / 256, CH), 256, 0, stream>>>(bufA, psum, psumsq, H1, rowsPer);
    col_stats2<<<H1 / 256, 256, 0, stream>>>(psum, psumsq, g1, be1, scale, shift, H1, CH, invB);
    norm_leaky<<<(unsigned)((size_t)B * H1 / 8 / 256), 256, 0, stream>>>(bufA, scale, shift, H1, (size_t)B * H1 / 8);

    // --- layer 2: [B,2048] x [2048,2048]^T, in place on bufA via row chunks ---
    for (int c = 0; c < B / RCH; ++c) {
        hipMemcpyAsync(scratch, bufA + (size_t)c * RCH * H1, (size_t)RCH * H1 * 2,
                       hipMemcpyDeviceToDevice, stream);
        gemm_bt<<<(RCH / 128) * (H2 / 128), 256, 0, stream>>>(
            scratch, W2b, b2, bufA + (size_t)c * RCH * H1, RCH, H2, H1);
    }
    col_stats1<<<dim3(H2 / 256, CH), 256, 0, stream>>>(bufA, psum, psumsq, H2, rowsPer);
    col_stats2<<<H2 / 256, 256, 0, stream>>>(psum, psumsq, g2, be2, scale, shift, H2, CH, invB);
    norm_leaky<<<(unsigned)((size_t)B * H2 / 8 / 256), 256, 0, stream>>>(bufA, scale, shift, H2, (size_t)B * H2 / 8);

    // --- layer 3: [B,2048] x [1024,2048]^T, in place (compacting) on bufA ---
    // chunk c writes elems [c*RCH*1024, (c+1)*RCH*1024) which never reach the
    // unread inputs of future chunks (starting at (c+1)*RCH*2048).
    for (int c = 0; c < B / RCH; ++c) {
        hipMemcpyAsync(scratch, bufA + (size_t)c * RCH * H2, (size_t)RCH * H2 * 2,
                       hipMemcpyDeviceToDevice, stream);
        gemm_bt<<<(RCH / 128) * (H3 / 128), 256, 0, stream>>>(
            scratch, W3b, b3, bufA + (size_t)c * RCH * H3, RCH, H3, H2);
    }
    col_stats1<<<dim3(H3 / 256, CH), 256, 0, stream>>>(bufA, psum, psumsq, H3, rowsPer);
    col_stats2<<<H3 / 256, 256, 0, stream>>>(psum, psumsq, g3, be3, scale, shift, H3, CH, invB);
    norm_leaky<<<(unsigned)((size_t)B * H3 / 8 / 256), 256, 0, stream>>>(bufA, scale, shift, H3, (size_t)B * H3 / 8);

    // --- output: [B,1024] . wout + bout ---
    matvec_out<<<B / 4, 256, 0, stream>>>(bufA, wout, bout, out, H3);
}

// Round 3
// 1203.582 us; speedup vs baseline: 1.4507x; 1.4507x over previous
//
#include <hip/hip_runtime.h>

typedef __bf16 bf16x8 __attribute__((ext_vector_type(8)));
typedef float f32x4 __attribute__((ext_vector_type(4)));
typedef unsigned short us8 __attribute__((ext_vector_type(8)));

typedef __attribute__((address_space(3))) void lds_void_t;
typedef const __attribute__((address_space(1))) void gbl_void_t;

__device__ __forceinline__ unsigned short f2bf(float f) {
    unsigned u = __builtin_bit_cast(unsigned, f);
    u += 0x7FFFu + ((u >> 16) & 1u);   // round-to-nearest-even
    return (unsigned short)(u >> 16);
}
__device__ __forceinline__ float bf2f(unsigned short h) {
    unsigned u = ((unsigned)h) << 16;
    return __builtin_bit_cast(float, u);
}

// ---------------- diagnostic: reveal ws_size via absmax if workspace too small ----
__global__ void report_ws(float* out, float v) { out[0] = v; }

// ---------------- f32 -> bf16 cast (vectorized) ----------------
__global__ __launch_bounds__(256) void cast_bf16(
    const float* __restrict__ src, unsigned short* __restrict__ dst, size_t n8)
{
    size_t i = (size_t)blockIdx.x * 256 + threadIdx.x;
    if (i >= n8) return;
    const float4* s = (const float4*)src + i * 2;
    float4 a = s[0], b = s[1];
    us8 o;
    o[0] = f2bf(a.x); o[1] = f2bf(a.y); o[2] = f2bf(a.z); o[3] = f2bf(a.w);
    o[4] = f2bf(b.x); o[5] = f2bf(b.y); o[6] = f2bf(b.z); o[7] = f2bf(b.w);
    *((us8*)dst + i) = o;
}

// ---------------- bf16 GEMM: Y = A @ W^T + bias (m97 structure) ----------------
// A [M,K] bf16 row-major, W [N,K] bf16 row-major, Y [M,N] bf16.
// 128x128 tile, BK=64, 256 threads (4 waves, 2x2), 16x16x32 MFMA, 4x4 frags/wave.
__global__ __launch_bounds__(256) void gemm_bt(
    const unsigned short* __restrict__ A,
    const unsigned short* __restrict__ W,
    const float* __restrict__ bias,
    unsigned short* __restrict__ Y,
    int M, int N, int K)
{
    __shared__ unsigned short As[128][64];
    __shared__ unsigned short Ws[128][64];

    const int nbx = N >> 7;
    const int nwg = gridDim.x;
    const int cpx = nwg >> 3;                 // nwg % 8 == 0 guaranteed by launch
    const int bid = blockIdx.x;
    const int swz = (bid & 7) * cpx + (bid >> 3);   // bijective XCD swizzle
    const int bm = swz / nbx;
    const int bn = swz % nbx;

    const int t    = threadIdx.x;
    const int wv   = t >> 6;
    const int lane = t & 63;
    const int wr   = (wv >> 1) << 6;          // wave row offset (0/64)
    const int wc   = (wv & 1) << 6;           // wave col offset (0/64)
    const int fr   = lane & 15;
    const int fq   = lane >> 4;

    // staging map: thread t loads 16B -> LDS linear byte offset t*16 within chunk
    const int srow = t >> 3;                  // 0..31 (row within 32-row chunk)
    const int scol = (t & 7) << 3;            // k element offset (0..56)
    const unsigned ldsOff = (unsigned)wv << 10;  // wave-uniform base; +lane*16 by HW

    const size_t baseA = (size_t)(bm << 7) * K;
    const size_t baseW = (size_t)(bn << 7) * K;

    f32x4 acc[4][4];
#pragma unroll
    for (int m = 0; m < 4; ++m)
#pragma unroll
        for (int n = 0; n < 4; ++n)
            acc[m][n] = (f32x4){0.f, 0.f, 0.f, 0.f};

    for (int k0 = 0; k0 < K; k0 += 64) {
#pragma unroll
        for (int c = 0; c < 4; ++c) {
            const unsigned short* ga = A + baseA + (size_t)(c * 32 + srow) * K + (k0 + scol);
            const unsigned short* gw = W + baseW + (size_t)(c * 32 + srow) * K + (k0 + scol);
            __builtin_amdgcn_global_load_lds((gbl_void_t*)ga,
                (lds_void_t*)((char*)&As[0][0] + c * 4096 + ldsOff), 16, 0, 0);
            __builtin_amdgcn_global_load_lds((gbl_void_t*)gw,
                (lds_void_t*)((char*)&Ws[0][0] + c * 4096 + ldsOff), 16, 0, 0);
        }
        __syncthreads();
#pragma unroll
        for (int kk = 0; kk < 2; ++kk) {
            bf16x8 af[4], wf[4];
#pragma unroll
            for (int m = 0; m < 4; ++m)
                af[m] = *(const bf16x8*)&As[wr + m * 16 + fr][kk * 32 + fq * 8];
#pragma unroll
            for (int n = 0; n < 4; ++n)
                wf[n] = *(const bf16x8*)&Ws[wc + n * 16 + fr][kk * 32 + fq * 8];
#pragma unroll
            for (int m = 0; m < 4; ++m)
#pragma unroll
                for (int n = 0; n < 4; ++n)
                    acc[m][n] = __builtin_amdgcn_mfma_f32_16x16x32_bf16(
                        af[m], wf[n], acc[m][n], 0, 0, 0);
        }
        __syncthreads();
    }

    // epilogue: +bias, write bf16. C/D map: col = lane&15, row = (lane>>4)*4 + r
#pragma unroll
    for (int n = 0; n < 4; ++n) {
        const int col = (bn << 7) + wc + n * 16 + fr;
        const float bv = bias[col];
#pragma unroll
        for (int m = 0; m < 4; ++m) {
            const int row0 = (bm << 7) + wr + m * 16 + fq * 4;
#pragma unroll
            for (int r = 0; r < 4; ++r)
                Y[(size_t)(row0 + r) * N + col] = f2bf(acc[m][n][r] + bv);
        }
    }
}

// ---------------- BN column stats, stage 1 (coalesced, deterministic) ----------------
// Each thread owns one us8 (8 adjacent cols); a block covers min(N,2048) cols and
// reads rows contiguously. nUs8 = N/8; repeats = 256/nUs8 (1 for N=2048, 2 for N=1024).
// Partial chunk index = blockIdx.y*repeats + sub.
__global__ __launch_bounds__(256) void col_stats1(
    const unsigned short* __restrict__ Y, float* __restrict__ psum,
    float* __restrict__ psumsq, int N, int rowsPerBlock)
{
    const int nUs8 = N >> 3;
    const int sub  = threadIdx.x / nUs8;           // 0 or 1
    const int u8i  = threadIdx.x % nUs8;
    const int repeats = 256 / nUs8;
    const int myRows = rowsPerBlock / repeats;
    const int r0 = blockIdx.y * rowsPerBlock + sub * myRows;

    const us8* p = (const us8*)(Y + (size_t)r0 * N) + u8i;
    const int strideUs8 = nUs8;
    float s[8], ss[8];
#pragma unroll
    for (int e = 0; e < 8; ++e) { s[e] = 0.f; ss[e] = 0.f; }
    for (int r = 0; r < myRows; ++r) {
        us8 v = p[(size_t)r * strideUs8];
#pragma unroll
        for (int e = 0; e < 8; ++e) {
            float f = bf2f(v[e]);
            s[e] += f; ss[e] += f * f;
        }
    }
    const int chunk = blockIdx.y * repeats + sub;
    float* ps  = psum   + (size_t)chunk * N + u8i * 8;
    float* pss = psumsq + (size_t)chunk * N + u8i * 8;
#pragma unroll
    for (int e = 0; e < 8; ++e) { ps[e] = s[e]; pss[e] = ss[e]; }
}

// ---------------- BN stats, stage 2: finalize scale/shift ----------------
__global__ __launch_bounds__(256) void col_stats2(
    const float* __restrict__ psum, const float* __restrict__ psumsq,
    const float* __restrict__ g, const float* __restrict__ be,
    float* __restrict__ scale, float* __restrict__ shift,
    int N, int CHtot, float invM)
{
    const int col = blockIdx.x * 256 + threadIdx.x;
    float s = 0.f, ss = 0.f;
    for (int c = 0; c < CHtot; ++c) {
        s  += psum  [(size_t)c * N + col];
        ss += psumsq[(size_t)c * N + col];
    }
    float mu  = s * invM;
    float var = ss * invM - mu * mu;   // biased var, matches torch BN normalization
    float a = g[col] * rsqrtf(var + 1e-5f);
    scale[col] = a;
    shift[col] = be[col] - mu * a;
}

// ---------------- fused normalize + LeakyReLU(0.5) + copy (replaces memcpy) -------
// colMask8 = N/8 - 1 (N power of two). src/dst distinct.
__global__ __launch_bounds__(256) void norm_copy(
    const unsigned short* __restrict__ src, unsigned short* __restrict__ dst,
    const float* __restrict__ scale, const float* __restrict__ shift,
    unsigned colMask8, size_t n8)
{
    size_t i = (size_t)blockIdx.x * 256 + threadIdx.x;
    if (i >= n8) return;
    us8 v = *((const us8*)src + i);
    const unsigned c8 = (unsigned)i & colMask8;       // us8-granular column
    const float4* sc = (const float4*)scale + c8 * 2;
    const float4* sh = (const float4*)shift + c8 * 2;
    float4 s0 = sc[0], s1 = sc[1], h0 = sh[0], h1 = sh[1];
    float xs[8];
    xs[0] = bf2f(v[0]) * s0.x + h0.x;  xs[1] = bf2f(v[1]) * s0.y + h0.y;
    xs[2] = bf2f(v[2]) * s0.z + h0.z;  xs[3] = bf2f(v[3]) * s0.w + h0.w;
    xs[4] = bf2f(v[4]) * s1.x + h1.x;  xs[5] = bf2f(v[5]) * s1.y + h1.y;
    xs[6] = bf2f(v[6]) * s1.z + h1.z;  xs[7] = bf2f(v[7]) * s1.w + h1.w;
    us8 o;
#pragma unroll
    for (int j = 0; j < 8; ++j) {
        float x = xs[j];
        x = (x >= 0.f) ? x : 0.5f * x;
        o[j] = f2bf(x);
    }
    *((us8*)dst + i) = o;
}

// ---------------- final matvec with fused norm+leaky on X ----------------
// out[i] = sum_j leaky(scale[j]*X[i,j]+shift[j]) * wout[j] + bout
__global__ __launch_bounds__(256) void matvec_norm_out(
    const unsigned short* __restrict__ X, const float* __restrict__ scale,
    const float* __restrict__ shift, const float* __restrict__ wvec,
    const float* __restrict__ bout, float* __restrict__ out, int Kd)
{
    const int row  = blockIdx.x * 4 + (threadIdx.x >> 6);
    const int lane = threadIdx.x & 63;
    const unsigned short* xr = X + (size_t)row * Kd;
    float s = 0.f;
    for (int j = lane * 8; j < Kd; j += 512) {
        us8 x = *(const us8*)(xr + j);
        const float4* sc = (const float4*)(scale + j);
        const float4* sh = (const float4*)(shift + j);
        const float4* wv = (const float4*)(wvec + j);
        float4 s0 = sc[0], s1 = sc[1], h0 = sh[0], h1 = sh[1];
        float4 w0 = wv[0], w1 = wv[1];
        float xs[8] = {
            bf2f(x[0]) * s0.x + h0.x, bf2f(x[1]) * s0.y + h0.y,
            bf2f(x[2]) * s0.z + h0.z, bf2f(x[3]) * s0.w + h0.w,
            bf2f(x[4]) * s1.x + h1.x, bf2f(x[5]) * s1.y + h1.y,
            bf2f(x[6]) * s1.z + h1.z, bf2f(x[7]) * s1.w + h1.w };
        float wf[8] = { w0.x, w0.y, w0.z, w0.w, w1.x, w1.y, w1.z, w1.w };
#pragma unroll
        for (int e = 0; e < 8; ++e) {
            float xv = xs[e];
            xv = (xv >= 0.f) ? xv : 0.5f * xv;
            s += f2bf(xv) ? 0.f : 0.f, s += bf2f(f2bf(xv)) * wf[e];  // bf16-quantize like stored path
        }
    }
#pragma unroll
    for (int off = 32; off > 0; off >>= 1) s += __shfl_down(s, off);
    if (lane == 0) out[row] = s + bout[0];
}

extern "C" void kernel_launch(void* const* d_in, const int* in_sizes, int n_in,
                              void* d_out, int out_size, void* d_ws, size_t ws_size,
                              hipStream_t stream)
{
    const float* x    = (const float*)d_in[0];
    const float* w1   = (const float*)d_in[1];
    const float* b1   = (const float*)d_in[2];
    const float* g1   = (const float*)d_in[3];
    const float* be1  = (const float*)d_in[4];
    const float* w2   = (const float*)d_in[5];
    const float* b2   = (const float*)d_in[6];
    const float* g2   = (const float*)d_in[7];
    const float* be2  = (const float*)d_in[8];
    const float* w3   = (const float*)d_in[9];
    const float* b3   = (const float*)d_in[10];
    const float* g3   = (const float*)d_in[11];
    const float* be3  = (const float*)d_in[12];
    const float* wout = (const float*)d_in[13];
    const float* bout = (const float*)d_in[14];
    float* out = (float*)d_out;

    const int B = 32768, D = 512, H1 = 2048, H2 = 2048, H3 = 1024;
    const int CH = 128;                 // row chunks for stats (blocks in grid.y)
    const int rowsPerBlock = B / CH;    // 256
    const int RCH = 8192;               // row chunk for in-place GEMM (4 chunks)

    char* ws = (char*)d_ws;
    size_t off = 0;
    auto alloc = [&](size_t bytes) -> char* {
        char* p = ws + off;
        off += (bytes + 255) & ~(size_t)255;
        return p;
    };
    unsigned short* bufA    = (unsigned short*)alloc((size_t)B * H1 * 2);      // 134.2 MB
    unsigned short* scratch = (unsigned short*)alloc((size_t)RCH * H1 * 2);    //  33.6 MB
    unsigned short* W1b     = (unsigned short*)alloc((size_t)H1 * D * 2);      //   2.1 MB
    unsigned short* W2b     = (unsigned short*)alloc((size_t)H2 * H1 * 2);     //   8.4 MB
    unsigned short* W3b     = (unsigned short*)alloc((size_t)H3 * H2 * 2);     //   4.2 MB
    float* psum   = (float*)alloc((size_t)2 * CH * H1 * 4);                    //   2.1 MB
    float* psumsq = (float*)alloc((size_t)2 * CH * H1 * 4);                    //   2.1 MB
    float* scale  = (float*)alloc((size_t)H1 * 4);
    float* shift  = (float*)alloc((size_t)H1 * 4);

    if (off > ws_size) {                // workspace too small: report its size via absmax
        report_ws<<<1, 1, 0, stream>>>(out, (float)ws_size);
        return;
    }

    // --- input casts to bf16 (x goes into scratch: B*D == RCH*H1 elements) ---
    {
        size_t n8;
        n8 = (size_t)B * D / 8;   cast_bf16<<<(unsigned)((n8 + 255) / 256), 256, 0, stream>>>(x,  scratch, n8);
        n8 = (size_t)H1 * D / 8;  cast_bf16<<<(unsigned)((n8 + 255) / 256), 256, 0, stream>>>(w1, W1b, n8);
        n8 = (size_t)H2 * H1 / 8; cast_bf16<<<(unsigned)((n8 + 255) / 256), 256, 0, stream>>>(w2, W2b, n8);
        n8 = (size_t)H3 * H2 / 8; cast_bf16<<<(unsigned)((n8 + 255) / 256), 256, 0, stream>>>(w3, W3b, n8);
    }

    const float invB = 1.0f / (float)B;
    const size_t chunk8 = (size_t)RCH * H1 / 8;     // us8 count per 8192x2048 chunk

    // --- layer 1: [B,512] x [2048,512]^T -> bufA (raw linear+bias) ---
    gemm_bt<<<(B / 128) * (H1 / 128), 256, 0, stream>>>(scratch, W1b, b1, bufA, B, H1, D);
    col_stats1<<<dim3(1, CH), 256, 0, stream>>>(bufA, psum, psumsq, H1, rowsPerBlock);
    col_stats2<<<H1 / 256, 256, 0, stream>>>(psum, psumsq, g1, be1, scale, shift, H1, CH, invB);

    // --- layer 2: in place on bufA; norm(L1) fused into the chunk copy ---
    for (int c = 0; c < B / RCH; ++c) {
        norm_copy<<<(unsigned)(chunk8 / 256), 256, 0, stream>>>(
            bufA + (size_t)c * RCH * H1, scratch, scale, shift, H1 / 8 - 1, chunk8);
        gemm_bt<<<(RCH / 128) * (H2 / 128), 256, 0, stream>>>(
            scratch, W2b, b2, bufA + (size_t)c * RCH * H1, RCH, H2, H1);
    }
    col_stats1<<<dim3(1, CH), 256, 0, stream>>>(bufA, psum, psumsq, H2, rowsPerBlock);
    col_stats2<<<H2 / 256, 256, 0, stream>>>(psum, psumsq, g2, be2, scale, shift, H2, CH, invB);

    // --- layer 3: in place (compacting); norm(L2) fused into the chunk copy ---
    for (int c = 0; c < B / RCH; ++c) {
        norm_copy<<<(unsigned)(chunk8 / 256), 256, 0, stream>>>(
            bufA + (size_t)c * RCH * H2, scratch, scale, shift, H2 / 8 - 1, chunk8);
        gemm_bt<<<(RCH / 128) * (H3 / 128), 256, 0, stream>>>(
            scratch, W3b, b3, bufA + (size_t)c * RCH * H3, RCH, H3, H2);
    }
    col_stats1<<<dim3(1, CH), 256, 0, stream>>>(bufA, psum, psumsq, H3, rowsPerBlock);
    col_stats2<<<H3 / 256, 256, 0, stream>>>(psum, psumsq, g3, be3, scale, shift, H3, 2 * CH, invB);

    // --- output: norm(L3) fused into the matvec ---
    matvec_norm_out<<<B / 4, 256, 0, stream>>>(bufA, scale, shift, wout, bout, out, H3);
}

// Round 4
// 1103.117 us; speedup vs baseline: 1.5828x; 1.0911x over previous
//
#include <hip/hip_runtime.h>

typedef __bf16 bf16x8 __attribute__((ext_vector_type(8)));
typedef float f32x4 __attribute__((ext_vector_type(4)));
typedef unsigned short us8 __attribute__((ext_vector_type(8)));

typedef __attribute__((address_space(3))) void lds_void_t;
typedef const __attribute__((address_space(1))) void gbl_void_t;

__device__ __forceinline__ unsigned short f2bf(float f) {
    unsigned u = __builtin_bit_cast(unsigned, f);
    u += 0x7FFFu + ((u >> 16) & 1u);   // round-to-nearest-even
    return (unsigned short)(u >> 16);
}
__device__ __forceinline__ float bf2f(unsigned short h) {
    unsigned u = ((unsigned)h) << 16;
    return __builtin_bit_cast(float, u);
}

// ---------------- diagnostic: reveal ws_size via absmax if workspace too small ----
__global__ void report_ws(float* out, float v) { out[0] = v; }

// ---------------- f32 -> bf16 cast (vectorized) ----------------
__global__ __launch_bounds__(256) void cast_bf16(
    const float* __restrict__ src, unsigned short* __restrict__ dst, size_t n8)
{
    size_t i = (size_t)blockIdx.x * 256 + threadIdx.x;
    if (i >= n8) return;
    const float4* s = (const float4*)src + i * 2;
    float4 a = s[0], b = s[1];
    us8 o;
    o[0] = f2bf(a.x); o[1] = f2bf(a.y); o[2] = f2bf(a.z); o[3] = f2bf(a.w);
    o[4] = f2bf(b.x); o[5] = f2bf(b.y); o[6] = f2bf(b.z); o[7] = f2bf(b.w);
    *((us8*)dst + i) = o;
}

// ---------------- bf16 GEMM: Y = A @ W^T + bias, fused BN column partials -------
// A [M,K] bf16 row-major, W [N,K] bf16 row-major, Y [M,N] bf16.
// 128x128 tile, BK=64, 256 threads (4 waves, 2x2), 16x16x32 MFMA, 4x4 frags/wave.
// Epilogue: (1) deterministic per-block column sum/sumsq -> psum/psumsq[rowBlk][col]
//           (2) C staged to LDS as bf16, then coalesced us8 (16B) stores.
__global__ __launch_bounds__(256) void gemm_bt(
    const unsigned short* __restrict__ A,
    const unsigned short* __restrict__ W,
    const float* __restrict__ bias,
    unsigned short* __restrict__ Y,
    float* __restrict__ psum, float* __restrict__ psumsq,
    int M, int N, int K, int rowBlkBase)
{
    __shared__ unsigned short As[128][64];
    __shared__ unsigned short Ws[128][64];

    const int nbx = N >> 7;
    const int nwg = gridDim.x;
    const int cpx = nwg >> 3;                 // nwg % 8 == 0 guaranteed by launch
    const int bid = blockIdx.x;
    const int swz = (bid & 7) * cpx + (bid >> 3);   // bijective XCD swizzle
    const int bm = swz / nbx;
    const int bn = swz % nbx;

    const int t    = threadIdx.x;
    const int wv   = t >> 6;
    const int lane = t & 63;
    const int wr   = (wv >> 1) << 6;          // wave row offset (0/64)
    const int wc   = (wv & 1) << 6;           // wave col offset (0/64)
    const int fr   = lane & 15;
    const int fq   = lane >> 4;

    // staging map: thread t loads 16B -> LDS linear byte offset t*16 within chunk
    const int srow = t >> 3;                  // 0..31 (row within 32-row chunk)
    const int scol = (t & 7) << 3;            // k element offset (0..56)
    const unsigned ldsOff = (unsigned)wv << 10;  // wave-uniform base; +lane*16 by HW

    const size_t baseA = (size_t)(bm << 7) * K;
    const size_t baseW = (size_t)(bn << 7) * K;

    f32x4 acc[4][4];
#pragma unroll
    for (int m = 0; m < 4; ++m)
#pragma unroll
        for (int n = 0; n < 4; ++n)
            acc[m][n] = (f32x4){0.f, 0.f, 0.f, 0.f};

    for (int k0 = 0; k0 < K; k0 += 64) {
#pragma unroll
        for (int c = 0; c < 4; ++c) {
            const unsigned short* ga = A + baseA + (size_t)(c * 32 + srow) * K + (k0 + scol);
            const unsigned short* gw = W + baseW + (size_t)(c * 32 + srow) * K + (k0 + scol);
            __builtin_amdgcn_global_load_lds((gbl_void_t*)ga,
                (lds_void_t*)((char*)&As[0][0] + c * 4096 + ldsOff), 16, 0, 0);
            __builtin_amdgcn_global_load_lds((gbl_void_t*)gw,
                (lds_void_t*)((char*)&Ws[0][0] + c * 4096 + ldsOff), 16, 0, 0);
        }
        __syncthreads();
#pragma unroll
        for (int kk = 0; kk < 2; ++kk) {
            bf16x8 af[4], wf[4];
#pragma unroll
            for (int m = 0; m < 4; ++m)
                af[m] = *(const bf16x8*)&As[wr + m * 16 + fr][kk * 32 + fq * 8];
#pragma unroll
            for (int n = 0; n < 4; ++n)
                wf[n] = *(const bf16x8*)&Ws[wc + n * 16 + fr][kk * 32 + fq * 8];
#pragma unroll
            for (int m = 0; m < 4; ++m)
#pragma unroll
                for (int n = 0; n < 4; ++n)
                    acc[m][n] = __builtin_amdgcn_mfma_f32_16x16x32_bf16(
                        af[m], wf[n], acc[m][n], 0, 0, 0);
        }
        __syncthreads();
    }

    // ---- epilogue ----
    // C/D map: col = lane&15 (+n*16+wc), row = (lane>>4)*4 + r (+m*16+wr)
    float bv4[4];
#pragma unroll
    for (int n = 0; n < 4; ++n) bv4[n] = bias[(bn << 7) + wc + n * 16 + fr];

    // (1) per-block column partial sums (alias As region; K-loop ended with barrier)
    float* psumsLDS  = (float*)&As[0][0];       // [128][8]
    float* psumsqLDS = psumsLDS + 128 * 8;      // [128][8]
#pragma unroll
    for (int n = 0; n < 4; ++n) {
        const int col = wc + n * 16 + fr;       // 0..127
        float s = 0.f, sq = 0.f;
#pragma unroll
        for (int m = 0; m < 4; ++m)
#pragma unroll
            for (int r = 0; r < 4; ++r) {
                float v = acc[m][n][r] + bv4[n];
                s += v; sq += v * v;
            }
        const int slot = fq + ((wv >> 1) << 2); // 0..7 (wave-row half x fq)
        psumsLDS [col * 8 + slot] = s;
        psumsqLDS[col * 8 + slot] = sq;
    }
    __syncthreads();
    if (t < 128) {
        float s = 0.f, sq = 0.f;
#pragma unroll
        for (int k = 0; k < 8; ++k) { s += psumsLDS[t * 8 + k]; sq += psumsqLDS[t * 8 + k]; }
        psum  [(size_t)(rowBlkBase + bm) * N + (bn << 7) + t] = s;
        psumsq[(size_t)(rowBlkBase + bm) * N + (bn << 7) + t] = sq;
    }
    __syncthreads();

    // (2) stage C bf16 into LDS (reuse As+Ws: 128x128x2B = 32 KB), coalesced writeout
    unsigned short* Cs = (unsigned short*)&As[0][0];
#pragma unroll
    for (int n = 0; n < 4; ++n) {
        const int col = wc + n * 16 + fr;
#pragma unroll
        for (int m = 0; m < 4; ++m) {
            const int row0 = wr + m * 16 + fq * 4;
#pragma unroll
            for (int r = 0; r < 4; ++r)
                Cs[(row0 + r) * 128 + col] = f2bf(acc[m][n][r] + bv4[n]);
        }
    }
    __syncthreads();
    {
        const size_t outBase = (size_t)(bm << 7) * N + (bn << 7);
#pragma unroll
        for (int i = 0; i < 8; ++i) {
            const int u   = t + i * 256;        // us8 index within tile [0,2048)
            const int row = u >> 4, c8 = u & 15;
            us8 v = *(const us8*)&Cs[row * 128 + c8 * 8];
            *(us8*)&Y[outBase + (size_t)row * N + c8 * 8] = v;
        }
    }
}

// ---------------- BN stats finalize: reduce row-block partials -> scale/shift ----
__global__ __launch_bounds__(256) void col_stats2(
    const float* __restrict__ psum, const float* __restrict__ psumsq,
    const float* __restrict__ g, const float* __restrict__ be,
    float* __restrict__ scale, float* __restrict__ shift,
    int N, int NB, float invM)
{
    const int col = blockIdx.x * 256 + threadIdx.x;
    float s = 0.f, ss = 0.f;
    for (int c = 0; c < NB; ++c) {
        s  += psum  [(size_t)c * N + col];
        ss += psumsq[(size_t)c * N + col];
    }
    float mu  = s * invM;
    float var = ss * invM - mu * mu;   // biased var, matches torch BN normalization
    float a = g[col] * rsqrtf(var + 1e-5f);
    scale[col] = a;
    shift[col] = be[col] - mu * a;
}

// ---------------- fused normalize + LeakyReLU(0.5) + copy (replaces memcpy) -------
// colMask8 = N/8 - 1 (N power of two). src/dst distinct.
__global__ __launch_bounds__(256) void norm_copy(
    const unsigned short* __restrict__ src, unsigned short* __restrict__ dst,
    const float* __restrict__ scale, const float* __restrict__ shift,
    unsigned colMask8, size_t n8)
{
    size_t i = (size_t)blockIdx.x * 256 + threadIdx.x;
    if (i >= n8) return;
    us8 v = *((const us8*)src + i);
    const unsigned c8 = (unsigned)i & colMask8;       // us8-granular column
    const float4* sc = (const float4*)scale + c8 * 2;
    const float4* sh = (const float4*)shift + c8 * 2;
    float4 s0 = sc[0], s1 = sc[1], h0 = sh[0], h1 = sh[1];
    float xs[8];
    xs[0] = bf2f(v[0]) * s0.x + h0.x;  xs[1] = bf2f(v[1]) * s0.y + h0.y;
    xs[2] = bf2f(v[2]) * s0.z + h0.z;  xs[3] = bf2f(v[3]) * s0.w + h0.w;
    xs[4] = bf2f(v[4]) * s1.x + h1.x;  xs[5] = bf2f(v[5]) * s1.y + h1.y;
    xs[6] = bf2f(v[6]) * s1.z + h1.z;  xs[7] = bf2f(v[7]) * s1.w + h1.w;
    us8 o;
#pragma unroll
    for (int j = 0; j < 8; ++j) {
        float x = xs[j];
        x = (x >= 0.f) ? x : 0.5f * x;
        o[j] = f2bf(x);
    }
    *((us8*)dst + i) = o;
}

// ---------------- final matvec with fused norm+leaky on X ----------------
// out[i] = sum_j leaky(scale[j]*X[i,j]+shift[j]) * wout[j] + bout
__global__ __launch_bounds__(256) void matvec_norm_out(
    const unsigned short* __restrict__ X, const float* __restrict__ scale,
    const float* __restrict__ shift, const float* __restrict__ wvec,
    const float* __restrict__ bout, float* __restrict__ out, int Kd)
{
    const int row  = blockIdx.x * 4 + (threadIdx.x >> 6);
    const int lane = threadIdx.x & 63;
    const unsigned short* xr = X + (size_t)row * Kd;
    float s = 0.f;
    for (int j = lane * 8; j < Kd; j += 512) {
        us8 x = *(const us8*)(xr + j);
        const float4* sc = (const float4*)(scale + j);
        const float4* sh = (const float4*)(shift + j);
        const float4* wv = (const float4*)(wvec + j);
        float4 s0 = sc[0], s1 = sc[1], h0 = sh[0], h1 = sh[1];
        float4 w0 = wv[0], w1 = wv[1];
        float xs[8] = {
            bf2f(x[0]) * s0.x + h0.x, bf2f(x[1]) * s0.y + h0.y,
            bf2f(x[2]) * s0.z + h0.z, bf2f(x[3]) * s0.w + h0.w,
            bf2f(x[4]) * s1.x + h1.x, bf2f(x[5]) * s1.y + h1.y,
            bf2f(x[6]) * s1.z + h1.z, bf2f(x[7]) * s1.w + h1.w };
        float wf[8] = { w0.x, w0.y, w0.z, w0.w, w1.x, w1.y, w1.z, w1.w };
#pragma unroll
        for (int e = 0; e < 8; ++e) {
            float xv = xs[e];
            xv = (xv >= 0.f) ? xv : 0.5f * xv;
            s += xv * wf[e];
        }
    }
#pragma unroll
    for (int off = 32; off > 0; off >>= 1) s += __shfl_down(s, off);
    if (lane == 0) out[row] = s + bout[0];
}

extern "C" void kernel_launch(void* const* d_in, const int* in_sizes, int n_in,
                              void* d_out, int out_size, void* d_ws, size_t ws_size,
                              hipStream_t stream)
{
    const float* x    = (const float*)d_in[0];
    const float* w1   = (const float*)d_in[1];
    const float* b1   = (const float*)d_in[2];
    const float* g1   = (const float*)d_in[3];
    const float* be1  = (const float*)d_in[4];
    const float* w2   = (const float*)d_in[5];
    const float* b2   = (const float*)d_in[6];
    const float* g2   = (const float*)d_in[7];
    const float* be2  = (const float*)d_in[8];
    const float* w3   = (const float*)d_in[9];
    const float* b3   = (const float*)d_in[10];
    const float* g3   = (const float*)d_in[11];
    const float* be3  = (const float*)d_in[12];
    const float* wout = (const float*)d_in[13];
    const float* bout = (const float*)d_in[14];
    float* out = (float*)d_out;

    const int B = 32768, D = 512, H1 = 2048, H2 = 2048, H3 = 1024;
    const int NB = B / 128;             // 256 row-blocks of partial stats
    const int RCH = 8192;               // row chunk for in-place GEMM (4 chunks)

    char* ws = (char*)d_ws;
    size_t off = 0;
    auto alloc = [&](size_t bytes) -> char* {
        char* p = ws + off;
        off += (bytes + 255) & ~(size_t)255;
        return p;
    };
    unsigned short* bufA    = (unsigned short*)alloc((size_t)B * H1 * 2);      // 134.2 MB
    unsigned short* scratch = (unsigned short*)alloc((size_t)RCH * H1 * 2);    //  33.6 MB
    unsigned short* W1b     = (unsigned short*)alloc((size_t)H1 * D * 2);      //   2.1 MB
    unsigned short* W2b     = (unsigned short*)alloc((size_t)H2 * H1 * 2);     //   8.4 MB
    unsigned short* W3b     = (unsigned short*)alloc((size_t)H3 * H2 * 2);     //   4.2 MB
    float* psum   = (float*)alloc((size_t)NB * H1 * 4);                        //   2.1 MB
    float* psumsq = (float*)alloc((size_t)NB * H1 * 4);                        //   2.1 MB
    float* scale  = (float*)alloc((size_t)H1 * 4);
    float* shift  = (float*)alloc((size_t)H1 * 4);

    if (off > ws_size) {                // workspace too small: report its size via absmax
        report_ws<<<1, 1, 0, stream>>>(out, (float)ws_size);
        return;
    }

    // --- input casts to bf16 (x goes into scratch: B*D == RCH*H1 elements) ---
    {
        size_t n8;
        n8 = (size_t)B * D / 8;   cast_bf16<<<(unsigned)((n8 + 255) / 256), 256, 0, stream>>>(x,  scratch, n8);
        n8 = (size_t)H1 * D / 8;  cast_bf16<<<(unsigned)((n8 + 255) / 256), 256, 0, stream>>>(w1, W1b, n8);
        n8 = (size_t)H2 * H1 / 8; cast_bf16<<<(unsigned)((n8 + 255) / 256), 256, 0, stream>>>(w2, W2b, n8);
        n8 = (size_t)H3 * H2 / 8; cast_bf16<<<(unsigned)((n8 + 255) / 256), 256, 0, stream>>>(w3, W3b, n8);
    }

    const float invB = 1.0f / (float)B;
    const size_t chunk8 = (size_t)RCH * H1 / 8;     // us8 count per 8192x2048 chunk

    // --- layer 1: [B,512] x [2048,512]^T -> bufA (stats fused into epilogue) ---
    gemm_bt<<<(B / 128) * (H1 / 128), 256, 0, stream>>>(
        scratch, W1b, b1, bufA, psum, psumsq, B, H1, D, 0);
    col_stats2<<<H1 / 256, 256, 0, stream>>>(psum, psumsq, g1, be1, scale, shift, H1, NB, invB);

    // --- layer 2: in place on bufA; norm(L1) fused into the chunk copy ---
    for (int c = 0; c < B / RCH; ++c) {
        norm_copy<<<(unsigned)(chunk8 / 256), 256, 0, stream>>>(
            bufA + (size_t)c * RCH * H1, scratch, scale, shift, H1 / 8 - 1, chunk8);
        gemm_bt<<<(RCH / 128) * (H2 / 128), 256, 0, stream>>>(
            scratch, W2b, b2, bufA + (size_t)c * RCH * H1, psum, psumsq,
            RCH, H2, H1, c * (RCH / 128));
    }
    col_stats2<<<H2 / 256, 256, 0, stream>>>(psum, psumsq, g2, be2, scale, shift, H2, NB, invB);

    // --- layer 3: in place (compacting); norm(L2) fused into the chunk copy ---
    for (int c = 0; c < B / RCH; ++c) {
        norm_copy<<<(unsigned)(chunk8 / 256), 256, 0, stream>>>(
            bufA + (size_t)c * RCH * H2, scratch, scale, shift, H2 / 8 - 1, chunk8);
        gemm_bt<<<(RCH / 128) * (H3 / 128), 256, 0, stream>>>(
            scratch, W3b, b3, bufA + (size_t)c * RCH * H3, psum, psumsq,
            RCH, H3, H2, c * (RCH / 128));
    }
    col_stats2<<<H3 / 256, 256, 0, stream>>>(psum, psumsq, g3, be3, scale, shift, H3, NB, invB);

    // --- output: norm(L3) fused into the matvec ---
    matvec_norm_out<<<B / 4, 256, 0, stream>>>(bufA, scale, shift, wout, bout, out, H3);
}

// Round 5
// 819.574 us; speedup vs baseline: 2.1304x; 1.3460x over previous
//
#include <hip/hip_runtime.h>

typedef __bf16 bf16x8 __attribute__((ext_vector_type(8)));
typedef float f32x4 __attribute__((ext_vector_type(4)));
typedef unsigned short us8 __attribute__((ext_vector_type(8)));

typedef __attribute__((address_space(3))) void lds_void_t;
typedef const __attribute__((address_space(1))) void gbl_void_t;

__device__ __forceinline__ unsigned short f2bf(float f) {
    unsigned u = __builtin_bit_cast(unsigned, f);
    u += 0x7FFFu + ((u >> 16) & 1u);   // round-to-nearest-even
    return (unsigned short)(u >> 16);
}
__device__ __forceinline__ float bf2f(unsigned short h) {
    unsigned u = ((unsigned)h) << 16;
    return __builtin_bit_cast(float, u);
}

// ---------------- diagnostic: reveal ws_size via absmax if workspace too small ----
__global__ void report_ws(float* out, float v) { out[0] = v; }

// ---------------- f32 -> bf16 cast (vectorized) ----------------
__global__ __launch_bounds__(256) void cast_bf16(
    const float* __restrict__ src, unsigned short* __restrict__ dst, size_t n8)
{
    size_t i = (size_t)blockIdx.x * 256 + threadIdx.x;
    if (i >= n8) return;
    const float4* s = (const float4*)src + i * 2;
    float4 a = s[0], b = s[1];
    us8 o;
    o[0] = f2bf(a.x); o[1] = f2bf(a.y); o[2] = f2bf(a.z); o[3] = f2bf(a.w);
    o[4] = f2bf(b.x); o[5] = f2bf(b.y); o[6] = f2bf(b.z); o[7] = f2bf(b.w);
    *((us8*)dst + i) = o;
}

// ================= 256x256 8-phase bf16 GEMM (T2+T3+T4+T5) =================
// Y = A @ W^T + bias;  A [M,K], W [N,K] bf16 row-major, Y [M,N] bf16.
// 512 threads = 8 waves (2 row-halves x 4 col-quarters). BK=64, dbuf LDS 128 KiB.
// Per-wave output 128x64 = acc[8][4] 16x16 frags. Counted vmcnt(4), setprio MFMA.
// Swizzle: LDS 16B-slot ^= (row&7), applied on pre-swizzled global src + ds_read.
// Epilogue: fused bias + deterministic per-block column sum/sumsq partials.

#define LOAD_AQ(QH) \
  _Pragma("unroll") for (int mm = 0; mm < 4; ++mm) \
    _Pragma("unroll") for (int s = 0; s < 2; ++s) \
      aq[mm][s] = *(const bf16x8*)&lds[aoff + ((QH)*64 + mm*16 + fr)*64 + (((s*4 + fq) ^ w7) << 3)];

#define LOAD_BP(G) \
  _Pragma("unroll") for (int nn = 0; nn < 2; ++nn) \
    _Pragma("unroll") for (int s = 0; s < 2; ++s) \
      bq[(G)*2+nn][s] = *(const bf16x8*)&lds[boff + ((wc&1)*64 + ((G)*2+nn)*16 + fr)*64 + (((s*4 + fq) ^ w7) << 3)];

#define MFMA_QUAD(QH, G) \
  _Pragma("unroll") for (int mm = 0; mm < 4; ++mm) \
    _Pragma("unroll") for (int nn = 0; nn < 2; ++nn) \
      _Pragma("unroll") for (int s = 0; s < 2; ++s) \
        acc[(QH)*4+mm][(G)*2+nn] = __builtin_amdgcn_mfma_f32_16x16x32_bf16( \
            aq[mm][s], bq[(G)*2+nn][s], acc[(QH)*4+mm][(G)*2+nn], 0, 0, 0);

__global__ __launch_bounds__(512, 2) void gemm256(
    const unsigned short* __restrict__ A,
    const unsigned short* __restrict__ W,
    const float* __restrict__ bias,
    unsigned short* __restrict__ Y,
    float* __restrict__ psum, float* __restrict__ psumsq,
    int M, int N, int K, int rowBlkBase)
{
    __shared__ unsigned short lds[65536];   // [dbuf2][op2][half2][8192 elems] = 128 KiB

    const int nbx = N >> 8;
    const int nwg = gridDim.x;
    const int cpx = nwg >> 3;                        // nwg % 8 == 0 guaranteed
    const int bid = blockIdx.x;
    const int swzb = (bid & 7) * cpx + (bid >> 3);   // bijective XCD swizzle
    const int bm = swzb / nbx;
    const int bn = swzb % nbx;

    const int t    = threadIdx.x;
    const int wid  = t >> 6;
    const int lane = t & 63;
    const int wrh  = wid >> 2;        // row half (0/1): rows wrh*128..+127
    const int wc   = wid & 3;         // col quarter: cols wc*64..+63
    const int fr   = lane & 15;
    const int fq   = lane >> 4;
    const int w7   = fr & 7;

    // staging source map: thread t, load l in {0,1}: row = l*64 + (t>>3),
    // 16B slot = (t&7) ^ ((t>>3)&7)  (pre-swizzled so linear LDS == swizzled layout)
    const int r0s  = t >> 3;
    const int ce   = (((t & 7) ^ ((t >> 3) & 7)) << 3);   // col element

    const size_t baseA = (size_t)(bm << 8) * K;
    const size_t baseW = (size_t)(bn << 8) * K;
    const int NT = K >> 6;

    auto STAGE = [&](int b, int op, int h, int kt) {
        const unsigned short* gsrc = (op ? W : A)
            + (op ? baseW : baseA)
            + (size_t)((h << 7) + r0s) * K + (kt << 6) + ce;
        char* dst = (char*)lds + ((((b * 2 + op) * 2 + h) << 14) + (wid << 10));
        __builtin_amdgcn_global_load_lds((gbl_void_t*)gsrc, (lds_void_t*)dst, 16, 0, 0);
        __builtin_amdgcn_global_load_lds((gbl_void_t*)(gsrc + (size_t)64 * K),
                                         (lds_void_t*)(dst + 8192), 16, 0, 0);
    };

    f32x4 acc[8][4];
#pragma unroll
    for (int m = 0; m < 8; ++m)
#pragma unroll
        for (int n = 0; n < 4; ++n)
            acc[m][n] = (f32x4){0.f, 0.f, 0.f, 0.f};

    // ---- prologue: B(0), A(0), B(1); keep B(1) in flight ----
    STAGE(0, 1, 0, 0); STAGE(0, 1, 1, 0);
    STAGE(0, 0, 0, 0); STAGE(0, 0, 1, 0);
    if (NT > 1) { STAGE(1, 1, 0, 1); STAGE(1, 1, 1, 1); }
    asm volatile("s_waitcnt vmcnt(4)" ::: "memory");
    __builtin_amdgcn_s_barrier();

    bf16x8 aq[4][2], bq[4][2];

    for (int kt = 0; kt < NT; ++kt) {
        const int b = kt & 1;
        const unsigned aoff = (unsigned)(b * 4 + wrh) * 8192;
        const unsigned boff = (unsigned)(b * 4 + 2 + (wc >> 1)) * 8192;

        // ---- phase 0: A rows 0-3 + B cols 0-1; stage A0(kt+1) ----
        LOAD_AQ(0);
        LOAD_BP(0);
        if (kt + 1 < NT) STAGE(b ^ 1, 0, 0, kt + 1);
        __builtin_amdgcn_s_barrier();
        asm volatile("s_waitcnt lgkmcnt(0)" ::: "memory");
        __builtin_amdgcn_s_setprio(1);
        MFMA_QUAD(0, 0);
        __builtin_amdgcn_s_setprio(0);
        __builtin_amdgcn_s_barrier();

        // ---- phase 1: B cols 2-3; stage A1(kt+1) ----
        LOAD_BP(1);
        if (kt + 1 < NT) STAGE(b ^ 1, 0, 1, kt + 1);
        __builtin_amdgcn_s_barrier();
        asm volatile("s_waitcnt lgkmcnt(0)" ::: "memory");
        __builtin_amdgcn_s_setprio(1);
        MFMA_QUAD(0, 1);
        __builtin_amdgcn_s_setprio(0);
        __builtin_amdgcn_s_barrier();

        // ---- phase 2: A rows 4-7; stage B0(kt+2) ----
        LOAD_AQ(1);
        if (kt + 2 < NT) STAGE(b, 1, 0, kt + 2);
        __builtin_amdgcn_s_barrier();
        asm volatile("s_waitcnt lgkmcnt(0)" ::: "memory");
        __builtin_amdgcn_s_setprio(1);
        MFMA_QUAD(1, 0);
        __builtin_amdgcn_s_setprio(0);
        __builtin_amdgcn_s_barrier();

        // ---- phase 3: stage B1(kt+2); counted vmcnt; last quadrant ----
        if (kt + 2 < NT) {
            STAGE(b, 1, 1, kt + 2);
            asm volatile("s_waitcnt vmcnt(4)" ::: "memory");
        } else {
            asm volatile("s_waitcnt vmcnt(0)" ::: "memory");
        }
        __builtin_amdgcn_s_barrier();
        __builtin_amdgcn_s_setprio(1);
        MFMA_QUAD(1, 1);
        __builtin_amdgcn_s_setprio(0);
        __builtin_amdgcn_s_barrier();
    }

    // ---- epilogue: bias, deterministic column stats, direct C store ----
    float bv[4];
#pragma unroll
    for (int nn = 0; nn < 4; ++nn) bv[nn] = bias[(bn << 8) + wc * 64 + nn * 16 + fr];

    float* sSum = (float*)lds;             // [256 cols][8 slots]
    float* sSq  = (float*)lds + 256 * 8;   // [256 cols][8 slots]
#pragma unroll
    for (int nn = 0; nn < 4; ++nn) {
        float s = 0.f, q = 0.f;
#pragma unroll
        for (int mm = 0; mm < 8; ++mm)
#pragma unroll
            for (int r = 0; r < 4; ++r) {
                float v = acc[mm][nn][r] + bv[nn];
                s += v; q += v * v;
            }
        const int col = wc * 64 + nn * 16 + fr;
        const int sl  = wrh * 4 + fq;
        sSum[col * 8 + sl] = s;
        sSq [col * 8 + sl] = q;
    }
    __builtin_amdgcn_s_barrier();
    if (t < 256) {
        float s = 0.f, q = 0.f;
#pragma unroll
        for (int k = 0; k < 8; ++k) { s += sSum[t * 8 + k]; q += sSq[t * 8 + k]; }
        psum  [(size_t)(rowBlkBase + bm) * N + (bn << 8) + t] = s;
        psumsq[(size_t)(rowBlkBase + bm) * N + (bn << 8) + t] = q;
    }

#pragma unroll
    for (int nn = 0; nn < 4; ++nn) {
        const int col = (bn << 8) + wc * 64 + nn * 16 + fr;
#pragma unroll
        for (int mm = 0; mm < 8; ++mm) {
            const int row0 = (bm << 8) + wrh * 128 + mm * 16 + fq * 4;
#pragma unroll
            for (int r = 0; r < 4; ++r)
                Y[(size_t)(row0 + r) * N + col] = f2bf(acc[mm][nn][r] + bv[nn]);
        }
    }
}

// ---------------- BN stats finalize: reduce row-block partials -> scale/shift ----
__global__ __launch_bounds__(256) void col_stats2(
    const float* __restrict__ psum, const float* __restrict__ psumsq,
    const float* __restrict__ g, const float* __restrict__ be,
    float* __restrict__ scale, float* __restrict__ shift,
    int N, int NB, float invM)
{
    const int col = blockIdx.x * 256 + threadIdx.x;
    float s = 0.f, ss = 0.f;
    for (int c = 0; c < NB; ++c) {
        s  += psum  [(size_t)c * N + col];
        ss += psumsq[(size_t)c * N + col];
    }
    float mu  = s * invM;
    float var = ss * invM - mu * mu;   // biased var, matches torch BN normalization
    float a = g[col] * rsqrtf(var + 1e-5f);
    scale[col] = a;
    shift[col] = be[col] - mu * a;
}

// ---------------- fused normalize + LeakyReLU(0.5) + copy (replaces memcpy) -------
__global__ __launch_bounds__(256) void norm_copy(
    const unsigned short* __restrict__ src, unsigned short* __restrict__ dst,
    const float* __restrict__ scale, const float* __restrict__ shift,
    unsigned colMask8, size_t n8)
{
    size_t i = (size_t)blockIdx.x * 256 + threadIdx.x;
    if (i >= n8) return;
    us8 v = *((const us8*)src + i);
    const unsigned c8 = (unsigned)i & colMask8;       // us8-granular column
    const float4* sc = (const float4*)scale + c8 * 2;
    const float4* sh = (const float4*)shift + c8 * 2;
    float4 s0 = sc[0], s1 = sc[1], h0 = sh[0], h1 = sh[1];
    float xs[8];
    xs[0] = bf2f(v[0]) * s0.x + h0.x;  xs[1] = bf2f(v[1]) * s0.y + h0.y;
    xs[2] = bf2f(v[2]) * s0.z + h0.z;  xs[3] = bf2f(v[3]) * s0.w + h0.w;
    xs[4] = bf2f(v[4]) * s1.x + h1.x;  xs[5] = bf2f(v[5]) * s1.y + h1.y;
    xs[6] = bf2f(v[6]) * s1.z + h1.z;  xs[7] = bf2f(v[7]) * s1.w + h1.w;
    us8 o;
#pragma unroll
    for (int j = 0; j < 8; ++j) {
        float x = xs[j];
        x = (x >= 0.f) ? x : 0.5f * x;
        o[j] = f2bf(x);
    }
    *((us8*)dst + i) = o;
}

// ---------------- final matvec with fused norm+leaky on X ----------------
__global__ __launch_bounds__(256) void matvec_norm_out(
    const unsigned short* __restrict__ X, const float* __restrict__ scale,
    const float* __restrict__ shift, const float* __restrict__ wvec,
    const float* __restrict__ bout, float* __restrict__ out, int Kd)
{
    const int row  = blockIdx.x * 4 + (threadIdx.x >> 6);
    const int lane = threadIdx.x & 63;
    const unsigned short* xr = X + (size_t)row * Kd;
    float s = 0.f;
    for (int j = lane * 8; j < Kd; j += 512) {
        us8 x = *(const us8*)(xr + j);
        const float4* sc = (const float4*)(scale + j);
        const float4* sh = (const float4*)(shift + j);
        const float4* wv = (const float4*)(wvec + j);
        float4 s0 = sc[0], s1 = sc[1], h0 = sh[0], h1 = sh[1];
        float4 w0 = wv[0], w1 = wv[1];
        float xs[8] = {
            bf2f(x[0]) * s0.x + h0.x, bf2f(x[1]) * s0.y + h0.y,
            bf2f(x[2]) * s0.z + h0.z, bf2f(x[3]) * s0.w + h0.w,
            bf2f(x[4]) * s1.x + h1.x, bf2f(x[5]) * s1.y + h1.y,
            bf2f(x[6]) * s1.z + h1.z, bf2f(x[7]) * s1.w + h1.w };
        float wf[8] = { w0.x, w0.y, w0.z, w0.w, w1.x, w1.y, w1.z, w1.w };
#pragma unroll
        for (int e = 0; e < 8; ++e) {
            float xv = xs[e];
            xv = (xv >= 0.f) ? xv : 0.5f * xv;
            s += xv * wf[e];
        }
    }
#pragma unroll
    for (int off = 32; off > 0; off >>= 1) s += __shfl_down(s, off);
    if (lane == 0) out[row] = s + bout[0];
}

extern "C" void kernel_launch(void* const* d_in, const int* in_sizes, int n_in,
                              void* d_out, int out_size, void* d_ws, size_t ws_size,
                              hipStream_t stream)
{
    const float* x    = (const float*)d_in[0];
    const float* w1   = (const float*)d_in[1];
    const float* b1   = (const float*)d_in[2];
    const float* g1   = (const float*)d_in[3];
    const float* be1  = (const float*)d_in[4];
    const float* w2   = (const float*)d_in[5];
    const float* b2   = (const float*)d_in[6];
    const float* g2   = (const float*)d_in[7];
    const float* be2  = (const float*)d_in[8];
    const float* w3   = (const float*)d_in[9];
    const float* b3   = (const float*)d_in[10];
    const float* g3   = (const float*)d_in[11];
    const float* be3  = (const float*)d_in[12];
    const float* wout = (const float*)d_in[13];
    const float* bout = (const float*)d_in[14];
    float* out = (float*)d_out;

    const int B = 32768, D = 512, H1 = 2048, H2 = 2048, H3 = 1024;
    const int NB = B / 256;             // 128 row-blocks of partial stats
    const int RCH = 8192;               // row chunk for in-place GEMM (4 chunks)

    char* ws = (char*)d_ws;
    size_t off = 0;
    auto alloc = [&](size_t bytes) -> char* {
        char* p = ws + off;
        off += (bytes + 255) & ~(size_t)255;
        return p;
    };
    unsigned short* bufA    = (unsigned short*)alloc((size_t)B * H1 * 2);      // 134.2 MB
    unsigned short* scratch = (unsigned short*)alloc((size_t)RCH * H1 * 2);    //  33.6 MB
    unsigned short* W1b     = (unsigned short*)alloc((size_t)H1 * D * 2);      //   2.1 MB
    unsigned short* W2b     = (unsigned short*)alloc((size_t)H2 * H1 * 2);     //   8.4 MB
    unsigned short* W3b     = (unsigned short*)alloc((size_t)H3 * H2 * 2);     //   4.2 MB
    float* psum   = (float*)alloc((size_t)NB * H1 * 4);                        //   1.0 MB
    float* psumsq = (float*)alloc((size_t)NB * H1 * 4);                        //   1.0 MB
    float* scale  = (float*)alloc((size_t)H1 * 4);
    float* shift  = (float*)alloc((size_t)H1 * 4);

    if (off > ws_size) {                // workspace too small: report its size via absmax
        report_ws<<<1, 1, 0, stream>>>(out, (float)ws_size);
        return;
    }

    // --- input casts to bf16 (x goes into scratch: B*D == RCH*H1 elements) ---
    {
        size_t n8;
        n8 = (size_t)B * D / 8;   cast_bf16<<<(unsigned)((n8 + 255) / 256), 256, 0, stream>>>(x,  scratch, n8);
        n8 = (size_t)H1 * D / 8;  cast_bf16<<<(unsigned)((n8 + 255) / 256), 256, 0, stream>>>(w1, W1b, n8);
        n8 = (size_t)H2 * H1 / 8; cast_bf16<<<(unsigned)((n8 + 255) / 256), 256, 0, stream>>>(w2, W2b, n8);
        n8 = (size_t)H3 * H2 / 8; cast_bf16<<<(unsigned)((n8 + 255) / 256), 256, 0, stream>>>(w3, W3b, n8);
    }

    const float invB = 1.0f / (float)B;
    const size_t chunk8 = (size_t)RCH * H1 / 8;     // us8 count per 8192x2048 chunk

    // --- layer 1: [B,512] x [2048,512]^T -> bufA (stats fused into epilogue) ---
    gemm256<<<(B / 256) * (H1 / 256), 512, 0, stream>>>(
        scratch, W1b, b1, bufA, psum, psumsq, B, H1, D, 0);
    col_stats2<<<H1 / 256, 256, 0, stream>>>(psum, psumsq, g1, be1, scale, shift, H1, NB, invB);

    // --- layer 2: in place on bufA; norm(L1) fused into the chunk copy ---
    for (int c = 0; c < B / RCH; ++c) {
        norm_copy<<<(unsigned)(chunk8 / 256), 256, 0, stream>>>(
            bufA + (size_t)c * RCH * H1, scratch, scale, shift, H1 / 8 - 1, chunk8);
        gemm256<<<(RCH / 256) * (H2 / 256), 512, 0, stream>>>(
            scratch, W2b, b2, bufA + (size_t)c * RCH * H1, psum, psumsq,
            RCH, H2, H1, c * (RCH / 256));
    }
    col_stats2<<<H2 / 256, 256, 0, stream>>>(psum, psumsq, g2, be2, scale, shift, H2, NB, invB);

    // --- layer 3: in place (compacting); norm(L2) fused into the chunk copy ---
    for (int c = 0; c < B / RCH; ++c) {
        norm_copy<<<(unsigned)(chunk8 / 256), 256, 0, stream>>>(
            bufA + (size_t)c * RCH * H2, scratch, scale, shift, H2 / 8 - 1, chunk8);
        gemm256<<<(RCH / 256) * (H3 / 256), 512, 0, stream>>>(
            scratch, W3b, b3, bufA + (size_t)c * RCH * H3, psum, psumsq,
            RCH, H3, H2, c * (RCH / 256));
    }
    col_stats2<<<H3 / 256, 256, 0, stream>>>(psum, psumsq, g3, be3, scale, shift, H3, NB, invB);

    // --- output: norm(L3) fused into the matvec ---
    matvec_norm_out<<<B / 4, 256, 0, stream>>>(bufA, scale, shift, wout, bout, out, H3);
}

// Round 6
// 803.623 us; speedup vs baseline: 2.1727x; 1.0198x over previous
//
#include <hip/hip_runtime.h>

typedef __bf16 bf16x8 __attribute__((ext_vector_type(8)));
typedef float f32x4 __attribute__((ext_vector_type(4)));
typedef unsigned short us8 __attribute__((ext_vector_type(8)));

typedef __attribute__((address_space(3))) void lds_void_t;
typedef const __attribute__((address_space(1))) void gbl_void_t;

__device__ __forceinline__ unsigned short f2bf(float f) {
    unsigned u = __builtin_bit_cast(unsigned, f);
    u += 0x7FFFu + ((u >> 16) & 1u);   // round-to-nearest-even
    return (unsigned short)(u >> 16);
}
__device__ __forceinline__ float bf2f(unsigned short h) {
    unsigned u = ((unsigned)h) << 16;
    return __builtin_bit_cast(float, u);
}

// ---------------- diagnostic: reveal ws_size via absmax if workspace too small ----
__global__ void report_ws(float* out, float v) { out[0] = v; }

// ---------------- f32 -> bf16 cast (vectorized) ----------------
__global__ __launch_bounds__(256) void cast_bf16(
    const float* __restrict__ src, unsigned short* __restrict__ dst, size_t n8)
{
    size_t i = (size_t)blockIdx.x * 256 + threadIdx.x;
    if (i >= n8) return;
    const float4* s = (const float4*)src + i * 2;
    float4 a = s[0], b = s[1];
    us8 o;
    o[0] = f2bf(a.x); o[1] = f2bf(a.y); o[2] = f2bf(a.z); o[3] = f2bf(a.w);
    o[4] = f2bf(b.x); o[5] = f2bf(b.y); o[6] = f2bf(b.z); o[7] = f2bf(b.w);
    *((us8*)dst + i) = o;
}

// ================= 256x256 8-phase bf16 GEMM (T2+T3+T4+T5) =================
// Y = A @ W^T + bias;  A [M,K], W [N,K] bf16 row-major, Y [M,N] bf16.
// 512 threads = 8 waves (2 row-halves x 4 col-quarters). BK=64, dbuf LDS 128 KiB.
// Per-wave output 128x64 = acc[8][4] 16x16 frags. Counted vmcnt(4), setprio MFMA.
// Swizzle: LDS 16B-slot ^= (row&7), applied on pre-swizzled global src + ds_read.
// Epilogue: fused bias + deterministic column partials + LDS-staged coalesced C.

#define LOAD_AQ(QH) \
  _Pragma("unroll") for (int mm = 0; mm < 4; ++mm) \
    _Pragma("unroll") for (int s = 0; s < 2; ++s) \
      aq[mm][s] = *(const bf16x8*)&lds[aoff + ((QH)*64 + mm*16 + fr)*64 + (((s*4 + fq) ^ w7) << 3)];

#define LOAD_BP(G) \
  _Pragma("unroll") for (int nn = 0; nn < 2; ++nn) \
    _Pragma("unroll") for (int s = 0; s < 2; ++s) \
      bq[(G)*2+nn][s] = *(const bf16x8*)&lds[boff + ((wc&1)*64 + ((G)*2+nn)*16 + fr)*64 + (((s*4 + fq) ^ w7) << 3)];

#define MFMA_QUAD(QH, G) \
  _Pragma("unroll") for (int mm = 0; mm < 4; ++mm) \
    _Pragma("unroll") for (int nn = 0; nn < 2; ++nn) \
      _Pragma("unroll") for (int s = 0; s < 2; ++s) \
        acc[(QH)*4+mm][(G)*2+nn] = __builtin_amdgcn_mfma_f32_16x16x32_bf16( \
            aq[mm][s], bq[(G)*2+nn][s], acc[(QH)*4+mm][(G)*2+nn], 0, 0, 0);

__global__ __launch_bounds__(512, 2) void gemm256(
    const unsigned short* __restrict__ A,
    const unsigned short* __restrict__ W,
    const float* __restrict__ bias,
    unsigned short* __restrict__ Y,
    float* __restrict__ psum, float* __restrict__ psumsq,
    int M, int N, int K, int rowBlkBase)
{
    __shared__ unsigned short lds[65536];   // [dbuf2][op2][half2][8192 elems] = 128 KiB

    const int nbx = N >> 8;
    const int nwg = gridDim.x;
    const int cpx = nwg >> 3;                        // nwg % 8 == 0 guaranteed
    const int bid = blockIdx.x;
    const int swzb = (bid & 7) * cpx + (bid >> 3);   // bijective XCD swizzle
    const int bm = swzb / nbx;
    const int bn = swzb % nbx;

    const int t    = threadIdx.x;
    const int wid  = t >> 6;
    const int lane = t & 63;
    const int wrh  = wid >> 2;        // row half (0/1): rows wrh*128..+127
    const int wc   = wid & 3;         // col quarter: cols wc*64..+63
    const int fr   = lane & 15;
    const int fq   = lane >> 4;
    const int w7   = fr & 7;

    // staging source map: thread t, load l in {0,1}: row = l*64 + (t>>3),
    // 16B slot = (t&7) ^ ((t>>3)&7)  (pre-swizzled so linear LDS == swizzled layout)
    const int r0s  = t >> 3;
    const int ce   = (((t & 7) ^ ((t >> 3) & 7)) << 3);   // col element

    const size_t baseA = (size_t)(bm << 8) * K;
    const size_t baseW = (size_t)(bn << 8) * K;
    const int NT = K >> 6;

    auto STAGE = [&](int b, int op, int h, int kt) {
        const unsigned short* gsrc = (op ? W : A)
            + (op ? baseW : baseA)
            + (size_t)((h << 7) + r0s) * K + (kt << 6) + ce;
        char* dst = (char*)lds + ((((b * 2 + op) * 2 + h) << 14) + (wid << 10));
        __builtin_amdgcn_global_load_lds((gbl_void_t*)gsrc, (lds_void_t*)dst, 16, 0, 0);
        __builtin_amdgcn_global_load_lds((gbl_void_t*)(gsrc + (size_t)64 * K),
                                         (lds_void_t*)(dst + 8192), 16, 0, 0);
    };

    f32x4 acc[8][4];
#pragma unroll
    for (int m = 0; m < 8; ++m)
#pragma unroll
        for (int n = 0; n < 4; ++n)
            acc[m][n] = (f32x4){0.f, 0.f, 0.f, 0.f};

    // ---- prologue: B(0), A(0), B(1); keep B(1) in flight ----
    STAGE(0, 1, 0, 0); STAGE(0, 1, 1, 0);
    STAGE(0, 0, 0, 0); STAGE(0, 0, 1, 0);
    if (NT > 1) { STAGE(1, 1, 0, 1); STAGE(1, 1, 1, 1); }
    asm volatile("s_waitcnt vmcnt(4)" ::: "memory");
    __builtin_amdgcn_s_barrier();

    bf16x8 aq[4][2], bq[4][2];

    for (int kt = 0; kt < NT; ++kt) {
        const int b = kt & 1;
        const unsigned aoff = (unsigned)(b * 4 + wrh) * 8192;
        const unsigned boff = (unsigned)(b * 4 + 2 + (wc >> 1)) * 8192;

        // ---- phase 0: A rows 0-3 + B cols 0-1; stage A0(kt+1) ----
        LOAD_AQ(0);
        LOAD_BP(0);
        if (kt + 1 < NT) STAGE(b ^ 1, 0, 0, kt + 1);
        __builtin_amdgcn_s_barrier();
        asm volatile("s_waitcnt lgkmcnt(0)" ::: "memory");
        __builtin_amdgcn_s_setprio(1);
        MFMA_QUAD(0, 0);
        __builtin_amdgcn_s_setprio(0);
        __builtin_amdgcn_s_barrier();

        // ---- phase 1: B cols 2-3; stage A1(kt+1) ----
        LOAD_BP(1);
        if (kt + 1 < NT) STAGE(b ^ 1, 0, 1, kt + 1);
        __builtin_amdgcn_s_barrier();
        asm volatile("s_waitcnt lgkmcnt(0)" ::: "memory");
        __builtin_amdgcn_s_setprio(1);
        MFMA_QUAD(0, 1);
        __builtin_amdgcn_s_setprio(0);
        __builtin_amdgcn_s_barrier();

        // ---- phase 2: A rows 4-7; stage B0(kt+2) ----
        LOAD_AQ(1);
        if (kt + 2 < NT) STAGE(b, 1, 0, kt + 2);
        __builtin_amdgcn_s_barrier();
        asm volatile("s_waitcnt lgkmcnt(0)" ::: "memory");
        __builtin_amdgcn_s_setprio(1);
        MFMA_QUAD(1, 0);
        __builtin_amdgcn_s_setprio(0);
        __builtin_amdgcn_s_barrier();

        // ---- phase 3: stage B1(kt+2); counted vmcnt; last quadrant ----
        if (kt + 2 < NT) {
            STAGE(b, 1, 1, kt + 2);
            asm volatile("s_waitcnt vmcnt(4)" ::: "memory");
        } else {
            asm volatile("s_waitcnt vmcnt(0)" ::: "memory");
        }
        __builtin_amdgcn_s_barrier();
        __builtin_amdgcn_s_setprio(1);
        MFMA_QUAD(1, 1);
        __builtin_amdgcn_s_setprio(0);
        __builtin_amdgcn_s_barrier();
    }

    // ---- epilogue: bias, deterministic column stats, LDS-staged coalesced C ----
    float bv[4];
#pragma unroll
    for (int nn = 0; nn < 4; ++nn) bv[nn] = bias[(bn << 8) + wc * 64 + nn * 16 + fr];

    // (1) column partial sums -> psum/psumsq (K-loop ended with a barrier)
    float* sSum = (float*)lds;             // [256 cols][8 slots]
    float* sSq  = (float*)lds + 256 * 8;   // [256 cols][8 slots]
#pragma unroll
    for (int nn = 0; nn < 4; ++nn) {
        float s = 0.f, q = 0.f;
#pragma unroll
        for (int mm = 0; mm < 8; ++mm)
#pragma unroll
            for (int r = 0; r < 4; ++r) {
                float v = acc[mm][nn][r] + bv[nn];
                s += v; q += v * v;
            }
        const int col = wc * 64 + nn * 16 + fr;
        const int sl  = wrh * 4 + fq;
        sSum[col * 8 + sl] = s;
        sSq [col * 8 + sl] = q;
    }
    __syncthreads();
    if (t < 256) {
        float s = 0.f, q = 0.f;
#pragma unroll
        for (int k = 0; k < 8; ++k) { s += sSum[t * 8 + k]; q += sSq[t * 8 + k]; }
        psum  [(size_t)(rowBlkBase + bm) * N + (bn << 8) + t] = s;
        psumsq[(size_t)(rowBlkBase + bm) * N + (bn << 8) + t] = q;
    }
    __syncthreads();

    // (2) stage C-tile bf16 into the (now dead) 128 KiB LDS: [256 rows][256 cols]
#pragma unroll
    for (int nn = 0; nn < 4; ++nn) {
        const int col = wc * 64 + nn * 16 + fr;
#pragma unroll
        for (int mm = 0; mm < 8; ++mm) {
            const int row0 = wrh * 128 + mm * 16 + fq * 4;
#pragma unroll
            for (int r = 0; r < 4; ++r)
                lds[(row0 + r) * 256 + col] = f2bf(acc[mm][nn][r] + bv[nn]);
        }
    }
    __syncthreads();

    // (3) coalesced write-out: 16 us8 (16B) stores per thread, 1 KiB per wave-op
    {
        const size_t outBase = (size_t)(bm << 8) * N + (bn << 8);
#pragma unroll
        for (int i = 0; i < 16; ++i) {
            const int u   = t + i * 512;        // us8 index within tile [0,8192)
            const int row = u >> 5, sl = u & 31;
            us8 v = *(const us8*)&lds[row * 256 + sl * 8];
            *(us8*)&Y[outBase + (size_t)row * N + sl * 8] = v;
        }
    }
}

// ---------------- BN stats finalize: reduce row-block partials -> scale/shift ----
__global__ __launch_bounds__(256) void col_stats2(
    const float* __restrict__ psum, const float* __restrict__ psumsq,
    const float* __restrict__ g, const float* __restrict__ be,
    float* __restrict__ scale, float* __restrict__ shift,
    int N, int NB, float invM)
{
    const int col = blockIdx.x * 256 + threadIdx.x;
    float s = 0.f, ss = 0.f;
    for (int c = 0; c < NB; ++c) {
        s  += psum  [(size_t)c * N + col];
        ss += psumsq[(size_t)c * N + col];
    }
    float mu  = s * invM;
    float var = ss * invM - mu * mu;   // biased var, matches torch BN normalization
    float a = g[col] * rsqrtf(var + 1e-5f);
    scale[col] = a;
    shift[col] = be[col] - mu * a;
}

// ---------------- fused normalize + LeakyReLU(0.5) + copy (replaces memcpy) -------
__global__ __launch_bounds__(256) void norm_copy(
    const unsigned short* __restrict__ src, unsigned short* __restrict__ dst,
    const float* __restrict__ scale, const float* __restrict__ shift,
    unsigned colMask8, size_t n8)
{
    size_t i = (size_t)blockIdx.x * 256 + threadIdx.x;
    if (i >= n8) return;
    us8 v = *((const us8*)src + i);
    const unsigned c8 = (unsigned)i & colMask8;       // us8-granular column
    const float4* sc = (const float4*)scale + c8 * 2;
    const float4* sh = (const float4*)shift + c8 * 2;
    float4 s0 = sc[0], s1 = sc[1], h0 = sh[0], h1 = sh[1];
    float xs[8];
    xs[0] = bf2f(v[0]) * s0.x + h0.x;  xs[1] = bf2f(v[1]) * s0.y + h0.y;
    xs[2] = bf2f(v[2]) * s0.z + h0.z;  xs[3] = bf2f(v[3]) * s0.w + h0.w;
    xs[4] = bf2f(v[4]) * s1.x + h1.x;  xs[5] = bf2f(v[5]) * s1.y + h1.y;
    xs[6] = bf2f(v[6]) * s1.z + h1.z;  xs[7] = bf2f(v[7]) * s1.w + h1.w;
    us8 o;
#pragma unroll
    for (int j = 0; j < 8; ++j) {
        float x = xs[j];
        x = (x >= 0.f) ? x : 0.5f * x;
        o[j] = f2bf(x);
    }
    *((us8*)dst + i) = o;
}

// ---------------- final matvec with fused norm+leaky on X ----------------
__global__ __launch_bounds__(256) void matvec_norm_out(
    const unsigned short* __restrict__ X, const float* __restrict__ scale,
    const float* __restrict__ shift, const float* __restrict__ wvec,
    const float* __restrict__ bout, float* __restrict__ out, int Kd)
{
    const int row  = blockIdx.x * 4 + (threadIdx.x >> 6);
    const int lane = threadIdx.x & 63;
    const unsigned short* xr = X + (size_t)row * Kd;
    float s = 0.f;
    for (int j = lane * 8; j < Kd; j += 512) {
        us8 x = *(const us8*)(xr + j);
        const float4* sc = (const float4*)(scale + j);
        const float4* sh = (const float4*)(shift + j);
        const float4* wv = (const float4*)(wvec + j);
        float4 s0 = sc[0], s1 = sc[1], h0 = sh[0], h1 = sh[1];
        float4 w0 = wv[0], w1 = wv[1];
        float xs[8] = {
            bf2f(x[0]) * s0.x + h0.x, bf2f(x[1]) * s0.y + h0.y,
            bf2f(x[2]) * s0.z + h0.z, bf2f(x[3]) * s0.w + h0.w,
            bf2f(x[4]) * s1.x + h1.x, bf2f(x[5]) * s1.y + h1.y,
            bf2f(x[6]) * s1.z + h1.z, bf2f(x[7]) * s1.w + h1.w };
        float wf[8] = { w0.x, w0.y, w0.z, w0.w, w1.x, w1.y, w1.z, w1.w };
#pragma unroll
        for (int e = 0; e < 8; ++e) {
            float xv = xs[e];
            xv = (xv >= 0.f) ? xv : 0.5f * xv;
            s += xv * wf[e];
        }
    }
#pragma unroll
    for (int off = 32; off > 0; off >>= 1) s += __shfl_down(s, off);
    if (lane == 0) out[row] = s + bout[0];
}

extern "C" void kernel_launch(void* const* d_in, const int* in_sizes, int n_in,
                              void* d_out, int out_size, void* d_ws, size_t ws_size,
                              hipStream_t stream)
{
    const float* x    = (const float*)d_in[0];
    const float* w1   = (const float*)d_in[1];
    const float* b1   = (const float*)d_in[2];
    const float* g1   = (const float*)d_in[3];
    const float* be1  = (const float*)d_in[4];
    const float* w2   = (const float*)d_in[5];
    const float* b2   = (const float*)d_in[6];
    const float* g2   = (const float*)d_in[7];
    const float* be2  = (const float*)d_in[8];
    const float* w3   = (const float*)d_in[9];
    const float* b3   = (const float*)d_in[10];
    const float* g3   = (const float*)d_in[11];
    const float* be3  = (const float*)d_in[12];
    const float* wout = (const float*)d_in[13];
    const float* bout = (const float*)d_in[14];
    float* out = (float*)d_out;

    const int B = 32768, D = 512, H1 = 2048, H2 = 2048, H3 = 1024;
    const int NB = B / 256;             // 128 row-blocks of partial stats
    const int RCH = 8192;               // row chunk for in-place GEMM (4 chunks)

    char* ws = (char*)d_ws;
    size_t off = 0;
    auto alloc = [&](size_t bytes) -> char* {
        char* p = ws + off;
        off += (bytes + 255) & ~(size_t)255;
        return p;
    };
    unsigned short* bufA    = (unsigned short*)alloc((size_t)B * H1 * 2);      // 134.2 MB
    unsigned short* scratch = (unsigned short*)alloc((size_t)RCH * H1 * 2);    //  33.6 MB
    unsigned short* W1b     = (unsigned short*)alloc((size_t)H1 * D * 2);      //   2.1 MB
    unsigned short* W2b     = (unsigned short*)alloc((size_t)H2 * H1 * 2);     //   8.4 MB
    unsigned short* W3b     = (unsigned short*)alloc((size_t)H3 * H2 * 2);     //   4.2 MB
    float* psum   = (float*)alloc((size_t)NB * H1 * 4);                        //   1.0 MB
    float* psumsq = (float*)alloc((size_t)NB * H1 * 4);                        //   1.0 MB
    float* scale  = (float*)alloc((size_t)H1 * 4);
    float* shift  = (float*)alloc((size_t)H1 * 4);

    if (off > ws_size) {                // workspace too small: report its size via absmax
        report_ws<<<1, 1, 0, stream>>>(out, (float)ws_size);
        return;
    }

    // --- input casts to bf16 (x goes into scratch: B*D == RCH*H1 elements) ---
    {
        size_t n8;
        n8 = (size_t)B * D / 8;   cast_bf16<<<(unsigned)((n8 + 255) / 256), 256, 0, stream>>>(x,  scratch, n8);
        n8 = (size_t)H1 * D / 8;  cast_bf16<<<(unsigned)((n8 + 255) / 256), 256, 0, stream>>>(w1, W1b, n8);
        n8 = (size_t)H2 * H1 / 8; cast_bf16<<<(unsigned)((n8 + 255) / 256), 256, 0, stream>>>(w2, W2b, n8);
        n8 = (size_t)H3 * H2 / 8; cast_bf16<<<(unsigned)((n8 + 255) / 256), 256, 0, stream>>>(w3, W3b, n8);
    }

    const float invB = 1.0f / (float)B;
    const size_t chunk8 = (size_t)RCH * H1 / 8;     // us8 count per 8192x2048 chunk

    // --- layer 1: [B,512] x [2048,512]^T -> bufA (stats fused into epilogue) ---
    gemm256<<<(B / 256) * (H1 / 256), 512, 0, stream>>>(
        scratch, W1b, b1, bufA, psum, psumsq, B, H1, D, 0);
    col_stats2<<<H1 / 256, 256, 0, stream>>>(psum, psumsq, g1, be1, scale, shift, H1, NB, invB);

    // --- layer 2: in place on bufA; norm(L1) fused into the chunk copy ---
    for (int c = 0; c < B / RCH; ++c) {
        norm_copy<<<(unsigned)(chunk8 / 256), 256, 0, stream>>>(
            bufA + (size_t)c * RCH * H1, scratch, scale, shift, H1 / 8 - 1, chunk8);
        gemm256<<<(RCH / 256) * (H2 / 256), 512, 0, stream>>>(
            scratch, W2b, b2, bufA + (size_t)c * RCH * H1, psum, psumsq,
            RCH, H2, H1, c * (RCH / 256));
    }
    col_stats2<<<H2 / 256, 256, 0, stream>>>(psum, psumsq, g2, be2, scale, shift, H2, NB, invB);

    // --- layer 3: in place (compacting); norm(L2) fused into the chunk copy ---
    for (int c = 0; c < B / RCH; ++c) {
        norm_copy<<<(unsigned)(chunk8 / 256), 256, 0, stream>>>(
            bufA + (size_t)c * RCH * H2, scratch, scale, shift, H2 / 8 - 1, chunk8);
        gemm256<<<(RCH / 256) * (H3 / 256), 512, 0, stream>>>(
            scratch, W3b, b3, bufA + (size_t)c * RCH * H3, psum, psumsq,
            RCH, H3, H2, c * (RCH / 256));
    }
    col_stats2<<<H3 / 256, 256, 0, stream>>>(psum, psumsq, g3, be3, scale, shift, H3, NB, invB);

    // --- output: norm(L3) fused into the matvec ---
    matvec_norm_out<<<B / 4, 256, 0, stream>>>(bufA, scale, shift, wout, bout, out, H3);
}

// Round 7
// 802.210 us; speedup vs baseline: 2.1765x; 1.0018x over previous
//
#include <hip/hip_runtime.h>

typedef __bf16 bf16x8 __attribute__((ext_vector_type(8)));
typedef float f32x4 __attribute__((ext_vector_type(4)));
typedef unsigned short us8 __attribute__((ext_vector_type(8)));

typedef __attribute__((address_space(3))) void lds_void_t;
typedef const __attribute__((address_space(1))) void gbl_void_t;

__device__ __forceinline__ unsigned short f2bf(float f) {
    unsigned u = __builtin_bit_cast(unsigned, f);
    u += 0x7FFFu + ((u >> 16) & 1u);   // round-to-nearest-even
    return (unsigned short)(u >> 16);
}
__device__ __forceinline__ float bf2f(unsigned short h) {
    unsigned u = ((unsigned)h) << 16;
    return __builtin_bit_cast(float, u);
}

// ---------------- diagnostic: reveal ws_size via absmax if workspace too small ----
__global__ void report_ws(float* out, float v) { out[0] = v; }

// ---------------- f32 -> bf16 cast (vectorized) ----------------
__global__ __launch_bounds__(256) void cast_bf16(
    const float* __restrict__ src, unsigned short* __restrict__ dst, size_t n8)
{
    size_t i = (size_t)blockIdx.x * 256 + threadIdx.x;
    if (i >= n8) return;
    const float4* s = (const float4*)src + i * 2;
    float4 a = s[0], b = s[1];
    us8 o;
    o[0] = f2bf(a.x); o[1] = f2bf(a.y); o[2] = f2bf(a.z); o[3] = f2bf(a.w);
    o[4] = f2bf(b.x); o[5] = f2bf(b.y); o[6] = f2bf(b.z); o[7] = f2bf(b.w);
    *((us8*)dst + i) = o;
}

// ================= 256x256 8-phase bf16 GEMM (T2+T3+T4+T5) =================
// Y = A @ W^T + bias;  A [M,K], W [N,K] bf16 row-major, Y [M,N] bf16.
// 512 threads = 8 waves (2 row-halves x 4 col-quarters). BK=64, dbuf LDS 128 KiB.
// Per-wave output 128x64 = acc[8][4] 16x16 frags. Counted vmcnt(4), setprio MFMA.
// Swizzle: LDS 16B-slot ^= (row&7), applied on pre-swizzled global src + ds_read.
// Epilogue: fused bias + deterministic column partials + LDS-staged coalesced C.

#define LOAD_AQ(QH) \
  _Pragma("unroll") for (int mm = 0; mm < 4; ++mm) \
    _Pragma("unroll") for (int s = 0; s < 2; ++s) \
      aq[mm][s] = *(const bf16x8*)&lds[aoff + ((QH)*64 + mm*16 + fr)*64 + (((s*4 + fq) ^ w7) << 3)];

#define LOAD_BP(G) \
  _Pragma("unroll") for (int nn = 0; nn < 2; ++nn) \
    _Pragma("unroll") for (int s = 0; s < 2; ++s) \
      bq[(G)*2+nn][s] = *(const bf16x8*)&lds[boff + ((wc&1)*64 + ((G)*2+nn)*16 + fr)*64 + (((s*4 + fq) ^ w7) << 3)];

#define MFMA_QUAD(QH, G) \
  _Pragma("unroll") for (int mm = 0; mm < 4; ++mm) \
    _Pragma("unroll") for (int nn = 0; nn < 2; ++nn) \
      _Pragma("unroll") for (int s = 0; s < 2; ++s) \
        acc[(QH)*4+mm][(G)*2+nn] = __builtin_amdgcn_mfma_f32_16x16x32_bf16( \
            aq[mm][s], bq[(G)*2+nn][s], acc[(QH)*4+mm][(G)*2+nn], 0, 0, 0);

__global__ __launch_bounds__(512, 2) void gemm256(
    const unsigned short* __restrict__ A,
    const unsigned short* __restrict__ W,
    const float* __restrict__ bias,
    unsigned short* __restrict__ Y,
    float* __restrict__ psum, float* __restrict__ psumsq,
    int M, int N, int K, int rowBlkBase)
{
    __shared__ unsigned short lds[65536];   // [dbuf2][op2][half2][8192 elems] = 128 KiB

    const int nbx = N >> 8;
    const int nwg = gridDim.x;
    const int cpx = nwg >> 3;                        // nwg % 8 == 0 guaranteed
    const int bid = blockIdx.x;
    const int swzb = (bid & 7) * cpx + (bid >> 3);   // bijective XCD swizzle
    const int bm = swzb / nbx;
    const int bn = swzb % nbx;

    const int t    = threadIdx.x;
    const int wid  = t >> 6;
    const int lane = t & 63;
    const int wrh  = wid >> 2;        // row half (0/1): rows wrh*128..+127
    const int wc   = wid & 3;         // col quarter: cols wc*64..+63
    const int fr   = lane & 15;
    const int fq   = lane >> 4;
    const int w7   = fr & 7;

    // staging source map: thread t, load l in {0,1}: row = l*64 + (t>>3),
    // 16B slot = (t&7) ^ ((t>>3)&7)  (pre-swizzled so linear LDS == swizzled layout)
    const int r0s  = t >> 3;
    const int ce   = (((t & 7) ^ ((t >> 3) & 7)) << 3);   // col element

    const size_t baseA = (size_t)(bm << 8) * K;
    const size_t baseW = (size_t)(bn << 8) * K;
    const int NT = K >> 6;

    auto STAGE = [&](int b, int op, int h, int kt) {
        const unsigned short* gsrc = (op ? W : A)
            + (op ? baseW : baseA)
            + (size_t)((h << 7) + r0s) * K + (kt << 6) + ce;
        char* dst = (char*)lds + ((((b * 2 + op) * 2 + h) << 14) + (wid << 10));
        __builtin_amdgcn_global_load_lds((gbl_void_t*)gsrc, (lds_void_t*)dst, 16, 0, 0);
        __builtin_amdgcn_global_load_lds((gbl_void_t*)(gsrc + (size_t)64 * K),
                                         (lds_void_t*)(dst + 8192), 16, 0, 0);
    };

    f32x4 acc[8][4];
#pragma unroll
    for (int m = 0; m < 8; ++m)
#pragma unroll
        for (int n = 0; n < 4; ++n)
            acc[m][n] = (f32x4){0.f, 0.f, 0.f, 0.f};

    // ---- prologue: B(0), A(0), B(1); keep B(1) in flight ----
    STAGE(0, 1, 0, 0); STAGE(0, 1, 1, 0);
    STAGE(0, 0, 0, 0); STAGE(0, 0, 1, 0);
    if (NT > 1) { STAGE(1, 1, 0, 1); STAGE(1, 1, 1, 1); }
    asm volatile("s_waitcnt vmcnt(4)" ::: "memory");
    __builtin_amdgcn_s_barrier();

    bf16x8 aq[4][2], bq[4][2];

    for (int kt = 0; kt < NT; ++kt) {
        const int b = kt & 1;
        const unsigned aoff = (unsigned)(b * 4 + wrh) * 8192;
        const unsigned boff = (unsigned)(b * 4 + 2 + (wc >> 1)) * 8192;

        // ---- phase 0: A rows 0-3 + B cols 0-1; stage A0(kt+1) ----
        LOAD_AQ(0);
        LOAD_BP(0);
        if (kt + 1 < NT) STAGE(b ^ 1, 0, 0, kt + 1);
        asm volatile("s_waitcnt lgkmcnt(8)" ::: "memory");   // throttle 12-read phase
        __builtin_amdgcn_s_barrier();
        asm volatile("s_waitcnt lgkmcnt(0)" ::: "memory");
        __builtin_amdgcn_s_setprio(1);
        MFMA_QUAD(0, 0);
        __builtin_amdgcn_s_setprio(0);
        __builtin_amdgcn_s_barrier();

        // ---- phase 1: B cols 2-3; stage A1(kt+1) ----
        LOAD_BP(1);
        if (kt + 1 < NT) STAGE(b ^ 1, 0, 1, kt + 1);
        __builtin_amdgcn_s_barrier();
        asm volatile("s_waitcnt lgkmcnt(0)" ::: "memory");
        __builtin_amdgcn_s_setprio(1);
        MFMA_QUAD(0, 1);
        __builtin_amdgcn_s_setprio(0);
        __builtin_amdgcn_s_barrier();

        // ---- phase 2: A rows 4-7; stage B0(kt+2) ----
        LOAD_AQ(1);
        if (kt + 2 < NT) STAGE(b, 1, 0, kt + 2);
        __builtin_amdgcn_s_barrier();
        asm volatile("s_waitcnt lgkmcnt(0)" ::: "memory");
        __builtin_amdgcn_s_setprio(1);
        MFMA_QUAD(1, 0);
        __builtin_amdgcn_s_setprio(0);
        __builtin_amdgcn_s_barrier();

        // ---- phase 3: stage B1(kt+2); counted vmcnt; last quadrant ----
        if (kt + 2 < NT) {
            STAGE(b, 1, 1, kt + 2);
            asm volatile("s_waitcnt vmcnt(4)" ::: "memory");
        } else {
            asm volatile("s_waitcnt vmcnt(0)" ::: "memory");
        }
        __builtin_amdgcn_s_barrier();
        __builtin_amdgcn_s_setprio(1);
        MFMA_QUAD(1, 1);
        __builtin_amdgcn_s_setprio(0);
        __builtin_amdgcn_s_barrier();
    }

    // ---- epilogue: bias, deterministic column stats, LDS-staged coalesced C ----
    float bv[4];
#pragma unroll
    for (int nn = 0; nn < 4; ++nn) bv[nn] = bias[(bn << 8) + wc * 64 + nn * 16 + fr];

    // (1) column partial sums -> psum/psumsq (K-loop ended with a barrier)
    float* sSum = (float*)lds;             // [256 cols][8 slots]
    float* sSq  = (float*)lds + 256 * 8;   // [256 cols][8 slots]
#pragma unroll
    for (int nn = 0; nn < 4; ++nn) {
        float s = 0.f, q = 0.f;
#pragma unroll
        for (int mm = 0; mm < 8; ++mm)
#pragma unroll
            for (int r = 0; r < 4; ++r) {
                float v = acc[mm][nn][r] + bv[nn];
                s += v; q += v * v;
            }
        const int col = wc * 64 + nn * 16 + fr;
        const int sl  = wrh * 4 + fq;
        sSum[col * 8 + sl] = s;
        sSq [col * 8 + sl] = q;
    }
    __syncthreads();
    if (t < 256) {
        float s = 0.f, q = 0.f;
#pragma unroll
        for (int k = 0; k < 8; ++k) { s += sSum[t * 8 + k]; q += sSq[t * 8 + k]; }
        psum  [(size_t)(rowBlkBase + bm) * N + (bn << 8) + t] = s;
        psumsq[(size_t)(rowBlkBase + bm) * N + (bn << 8) + t] = q;
    }
    __syncthreads();

    // (2) stage C-tile bf16 into the (now dead) 128 KiB LDS: [256 rows][256 cols]
#pragma unroll
    for (int nn = 0; nn < 4; ++nn) {
        const int col = wc * 64 + nn * 16 + fr;
#pragma unroll
        for (int mm = 0; mm < 8; ++mm) {
            const int row0 = wrh * 128 + mm * 16 + fq * 4;
#pragma unroll
            for (int r = 0; r < 4; ++r)
                lds[(row0 + r) * 256 + col] = f2bf(acc[mm][nn][r] + bv[nn]);
        }
    }
    __syncthreads();

    // (3) coalesced write-out: 16 us8 (16B) stores per thread, 1 KiB per wave-op
    {
        const size_t outBase = (size_t)(bm << 8) * N + (bn << 8);
#pragma unroll
        for (int i = 0; i < 16; ++i) {
            const int u   = t + i * 512;        // us8 index within tile [0,8192)
            const int row = u >> 5, sl = u & 31;
            us8 v = *(const us8*)&lds[row * 256 + sl * 8];
            *(us8*)&Y[outBase + (size_t)row * N + sl * 8] = v;
        }
    }
}

// ---------------- BN stats finalize: reduce row-block partials -> scale/shift ----
__global__ __launch_bounds__(256) void col_stats2(
    const float* __restrict__ psum, const float* __restrict__ psumsq,
    const float* __restrict__ g, const float* __restrict__ be,
    float* __restrict__ scale, float* __restrict__ shift,
    int N, int NB, float invM)
{
    const int col = blockIdx.x * 256 + threadIdx.x;
    float s = 0.f, ss = 0.f;
    for (int c = 0; c < NB; ++c) {
        s  += psum  [(size_t)c * N + col];
        ss += psumsq[(size_t)c * N + col];
    }
    float mu  = s * invM;
    float var = ss * invM - mu * mu;   // biased var, matches torch BN normalization
    float a = g[col] * rsqrtf(var + 1e-5f);
    scale[col] = a;
    shift[col] = be[col] - mu * a;
}

// ---------------- fused normalize + LeakyReLU(0.5) copy (grid-stride) -------------
__global__ __launch_bounds__(256) void norm_full(
    const unsigned short* __restrict__ src, unsigned short* __restrict__ dst,
    const float* __restrict__ scale, const float* __restrict__ shift,
    unsigned colMask8, size_t n8)
{
    const size_t stride = (size_t)gridDim.x * 256;
    for (size_t i = (size_t)blockIdx.x * 256 + threadIdx.x; i < n8; i += stride) {
        us8 v = *((const us8*)src + i);
        const unsigned c8 = (unsigned)i & colMask8;       // us8-granular column
        const float4* sc = (const float4*)scale + c8 * 2;
        const float4* sh = (const float4*)shift + c8 * 2;
        float4 s0 = sc[0], s1 = sc[1], h0 = sh[0], h1 = sh[1];
        float xs[8];
        xs[0] = bf2f(v[0]) * s0.x + h0.x;  xs[1] = bf2f(v[1]) * s0.y + h0.y;
        xs[2] = bf2f(v[2]) * s0.z + h0.z;  xs[3] = bf2f(v[3]) * s0.w + h0.w;
        xs[4] = bf2f(v[4]) * s1.x + h1.x;  xs[5] = bf2f(v[5]) * s1.y + h1.y;
        xs[6] = bf2f(v[6]) * s1.z + h1.z;  xs[7] = bf2f(v[7]) * s1.w + h1.w;
        us8 o;
#pragma unroll
        for (int j = 0; j < 8; ++j) {
            float x = xs[j];
            x = fmaxf(x, 0.5f * x);           // LeakyReLU(0.5) for any sign
            o[j] = f2bf(x);
        }
        *((us8*)dst + i) = o;
    }
}

// ---------------- final matvec with fused norm+leaky on X ----------------
__global__ __launch_bounds__(256) void matvec_norm_out(
    const unsigned short* __restrict__ X, const float* __restrict__ scale,
    const float* __restrict__ shift, const float* __restrict__ wvec,
    const float* __restrict__ bout, float* __restrict__ out, int Kd)
{
    const int row  = blockIdx.x * 4 + (threadIdx.x >> 6);
    const int lane = threadIdx.x & 63;
    const unsigned short* xr = X + (size_t)row * Kd;
    float s = 0.f;
    for (int j = lane * 8; j < Kd; j += 512) {
        us8 x = *(const us8*)(xr + j);
        const float4* sc = (const float4*)(scale + j);
        const float4* sh = (const float4*)(shift + j);
        const float4* wv = (const float4*)(wvec + j);
        float4 s0 = sc[0], s1 = sc[1], h0 = sh[0], h1 = sh[1];
        float4 w0 = wv[0], w1 = wv[1];
        float xs[8] = {
            bf2f(x[0]) * s0.x + h0.x, bf2f(x[1]) * s0.y + h0.y,
            bf2f(x[2]) * s0.z + h0.z, bf2f(x[3]) * s0.w + h0.w,
            bf2f(x[4]) * s1.x + h1.x, bf2f(x[5]) * s1.y + h1.y,
            bf2f(x[6]) * s1.z + h1.z, bf2f(x[7]) * s1.w + h1.w };
        float wf[8] = { w0.x, w0.y, w0.z, w0.w, w1.x, w1.y, w1.z, w1.w };
#pragma unroll
        for (int e = 0; e < 8; ++e) {
            float xv = xs[e];
            xv = fmaxf(xv, 0.5f * xv);
            s += xv * wf[e];
        }
    }
#pragma unroll
    for (int off = 32; off > 0; off >>= 1) s += __shfl_down(s, off);
    if (lane == 0) out[row] = s + bout[0];
}

extern "C" void kernel_launch(void* const* d_in, const int* in_sizes, int n_in,
                              void* d_out, int out_size, void* d_ws, size_t ws_size,
                              hipStream_t stream)
{
    const float* x    = (const float*)d_in[0];
    const float* w1   = (const float*)d_in[1];
    const float* b1   = (const float*)d_in[2];
    const float* g1   = (const float*)d_in[3];
    const float* be1  = (const float*)d_in[4];
    const float* w2   = (const float*)d_in[5];
    const float* b2   = (const float*)d_in[6];
    const float* g2   = (const float*)d_in[7];
    const float* be2  = (const float*)d_in[8];
    const float* w3   = (const float*)d_in[9];
    const float* b3   = (const float*)d_in[10];
    const float* g3   = (const float*)d_in[11];
    const float* be3  = (const float*)d_in[12];
    const float* wout = (const float*)d_in[13];
    const float* bout = (const float*)d_in[14];
    float* out = (float*)d_out;

    const int B = 32768, D = 512, H1 = 2048, H2 = 2048, H3 = 1024;
    const int NB = B / 256;             // 128 row-blocks of partial stats
    const float invB = 1.0f / (float)B;
    char* ws = (char*)d_ws;

    // ---------- Plan A: two full activation buffers (~283 MB) ----------
    {
        size_t off = 0;
        auto alloc = [&](size_t bytes) -> char* {
            char* p = ws + off;
            off += (bytes + 255) & ~(size_t)255;
            return p;
        };
        unsigned short* bufA = (unsigned short*)alloc((size_t)B * H1 * 2);   // 134.2 MB
        unsigned short* bufB = (unsigned short*)alloc((size_t)B * H1 * 2);   // 134.2 MB
        unsigned short* W2b  = (unsigned short*)alloc((size_t)H2 * H1 * 2);  //   8.4 MB
        unsigned short* W3b  = (unsigned short*)alloc((size_t)H3 * H2 * 2);  //   4.2 MB
        float* psum   = (float*)alloc((size_t)NB * H1 * 4);                  //   1.0 MB
        float* psumsq = (float*)alloc((size_t)NB * H1 * 4);                  //   1.0 MB
        float* scale  = (float*)alloc((size_t)H1 * 4);
        float* shift  = (float*)alloc((size_t)H1 * 4);
        // aliases inside bufB (both consumed by GEMM1, before bufB is written):
        unsigned short* W1b = bufB;                                          // 2.1 MB @ head
        unsigned short* Xb  = bufB + ((size_t)B * H1 - (size_t)B * D);       // 33.5 MB @ tail

        if (off <= ws_size) {
            size_t n8;
            n8 = (size_t)B * D / 8;   cast_bf16<<<(unsigned)((n8 + 255) / 256), 256, 0, stream>>>(x,  Xb,  n8);
            n8 = (size_t)H1 * D / 8;  cast_bf16<<<(unsigned)((n8 + 255) / 256), 256, 0, stream>>>(w1, W1b, n8);
            n8 = (size_t)H2 * H1 / 8; cast_bf16<<<(unsigned)((n8 + 255) / 256), 256, 0, stream>>>(w2, W2b, n8);
            n8 = (size_t)H3 * H2 / 8; cast_bf16<<<(unsigned)((n8 + 255) / 256), 256, 0, stream>>>(w3, W3b, n8);

            // layer 1: Xb @ W1^T -> bufA (raw)
            gemm256<<<(B / 256) * (H1 / 256), 512, 0, stream>>>(
                Xb, W1b, b1, bufA, psum, psumsq, B, H1, D, 0);
            col_stats2<<<H1 / 256, 256, 0, stream>>>(psum, psumsq, g1, be1, scale, shift, H1, NB, invB);
            norm_full<<<2048, 256, 0, stream>>>(bufA, bufB, scale, shift, H1 / 8 - 1, (size_t)B * H1 / 8);

            // layer 2: bufB @ W2^T -> bufA (raw)
            gemm256<<<(B / 256) * (H2 / 256), 512, 0, stream>>>(
                bufB, W2b, b2, bufA, psum, psumsq, B, H2, H1, 0);
            col_stats2<<<H2 / 256, 256, 0, stream>>>(psum, psumsq, g2, be2, scale, shift, H2, NB, invB);
            norm_full<<<2048, 256, 0, stream>>>(bufA, bufB, scale, shift, H2 / 8 - 1, (size_t)B * H2 / 8);

            // layer 3: bufB @ W3^T -> bufA (raw, compact)
            gemm256<<<(B / 256) * (H3 / 256), 512, 0, stream>>>(
                bufB, W3b, b3, bufA, psum, psumsq, B, H3, H2, 0);
            col_stats2<<<H3 / 256, 256, 0, stream>>>(psum, psumsq, g3, be3, scale, shift, H3, NB, invB);

            matvec_norm_out<<<B / 4, 256, 0, stream>>>(bufA, scale, shift, wout, bout, out, H3);
            return;
        }
    }

    // ---------- Plan B fallback: chunked in-place (round-6 path, ~185 MB) ----------
    {
        const int RCH = 8192;           // row chunk (4 chunks)
        size_t off = 0;
        auto alloc = [&](size_t bytes) -> char* {
            char* p = ws + off;
            off += (bytes + 255) & ~(size_t)255;
            return p;
        };
        unsigned short* bufA    = (unsigned short*)alloc((size_t)B * H1 * 2);
        unsigned short* scratch = (unsigned short*)alloc((size_t)RCH * H1 * 2);
        unsigned short* W1b     = (unsigned short*)alloc((size_t)H1 * D * 2);
        unsigned short* W2b     = (unsigned short*)alloc((size_t)H2 * H1 * 2);
        unsigned short* W3b     = (unsigned short*)alloc((size_t)H3 * H2 * 2);
        float* psum   = (float*)alloc((size_t)NB * H1 * 4);
        float* psumsq = (float*)alloc((size_t)NB * H1 * 4);
        float* scale  = (float*)alloc((size_t)H1 * 4);
        float* shift  = (float*)alloc((size_t)H1 * 4);

        if (off > ws_size) {            // even fallback doesn't fit: report ws_size
            report_ws<<<1, 1, 0, stream>>>(out, (float)ws_size);
            return;
        }

        size_t n8;
        n8 = (size_t)B * D / 8;   cast_bf16<<<(unsigned)((n8 + 255) / 256), 256, 0, stream>>>(x,  scratch, n8);
        n8 = (size_t)H1 * D / 8;  cast_bf16<<<(unsigned)((n8 + 255) / 256), 256, 0, stream>>>(w1, W1b, n8);
        n8 = (size_t)H2 * H1 / 8; cast_bf16<<<(unsigned)((n8 + 255) / 256), 256, 0, stream>>>(w2, W2b, n8);
        n8 = (size_t)H3 * H2 / 8; cast_bf16<<<(unsigned)((n8 + 255) / 256), 256, 0, stream>>>(w3, W3b, n8);

        const size_t chunk8 = (size_t)RCH * H1 / 8;

        gemm256<<<(B / 256) * (H1 / 256), 512, 0, stream>>>(
            scratch, W1b, b1, bufA, psum, psumsq, B, H1, D, 0);
        col_stats2<<<H1 / 256, 256, 0, stream>>>(psum, psumsq, g1, be1, scale, shift, H1, NB, invB);

        for (int c = 0; c < B / RCH; ++c) {
            norm_full<<<2048, 256, 0, stream>>>(
                bufA + (size_t)c * RCH * H1, scratch, scale, shift, H1 / 8 - 1, chunk8);
            gemm256<<<(RCH / 256) * (H2 / 256), 512, 0, stream>>>(
                scratch, W2b, b2, bufA + (size_t)c * RCH * H1, psum, psumsq,
                RCH, H2, H1, c * (RCH / 256));
        }
        col_stats2<<<H2 / 256, 256, 0, stream>>>(psum, psumsq, g2, be2, scale, shift, H2, NB, invB);

        for (int c = 0; c < B / RCH; ++c) {
            norm_full<<<2048, 256, 0, stream>>>(
                bufA + (size_t)c * RCH * H2, scratch, scale, shift, H2 / 8 - 1, chunk8);
            gemm256<<<(RCH / 256) * (H3 / 256), 512, 0, stream>>>(
                scratch, W3b, b3, bufA + (size_t)c * RCH * H3, psum, psumsq,
                RCH, H3, H2, c * (RCH / 256));
        }
        col_stats2<<<H3 / 256, 256, 0, stream>>>(psum, psumsq, g3, be3, scale, shift, H3, NB, invB);

        matvec_norm_out<<<B / 4, 256, 0, stream>>>(bufA, scale, shift, wout, bout, out, H3);
    }
}

// Round 8
// 682.284 us; speedup vs baseline: 2.5591x; 1.1758x over previous
//
#include <hip/hip_runtime.h>

typedef __bf16 bf16x8 __attribute__((ext_vector_type(8)));
typedef float f32x4 __attribute__((ext_vector_type(4)));
typedef unsigned short us8 __attribute__((ext_vector_type(8)));

typedef __attribute__((address_space(3))) void lds_void_t;
typedef const __attribute__((address_space(1))) void gbl_void_t;

__device__ __forceinline__ unsigned short f2bf(float f) {
    unsigned u = __builtin_bit_cast(unsigned, f);
    u += 0x7FFFu + ((u >> 16) & 1u);   // round-to-nearest-even
    return (unsigned short)(u >> 16);
}
__device__ __forceinline__ float bf2f(unsigned short h) {
    unsigned u = ((unsigned)h) << 16;
    return __builtin_bit_cast(float, u);
}

// ---------------- diagnostic: reveal ws_size via absmax if workspace too small ----
__global__ void report_ws(float* out, float v) { out[0] = v; }

// ---------------- f32 -> bf16 cast (vectorized) ----------------
__global__ __launch_bounds__(256) void cast_bf16(
    const float* __restrict__ src, unsigned short* __restrict__ dst, size_t n8)
{
    size_t i = (size_t)blockIdx.x * 256 + threadIdx.x;
    if (i >= n8) return;
    const float4* s = (const float4*)src + i * 2;
    float4 a = s[0], b = s[1];
    us8 o;
    o[0] = f2bf(a.x); o[1] = f2bf(a.y); o[2] = f2bf(a.z); o[3] = f2bf(a.w);
    o[4] = f2bf(b.x); o[5] = f2bf(b.y); o[6] = f2bf(b.z); o[7] = f2bf(b.w);
    *((us8*)dst + i) = o;
}

// ================= 256x256 8-phase bf16 GEMM (T2+T3+T4+T5) =================
// Y = A @ W^T + bias;  A [M,K], W [N,K] bf16 row-major, Y [M,N] bf16.
// 512 threads = 8 waves (2 row-halves x 4 col-quarters). BK=64, dbuf LDS 128 KiB.
// Per-wave output 128x64 = acc[8][4] 16x16 frags. Counted vmcnt(4), setprio MFMA.
// Swizzle: LDS 16B-slot ^= (row&7), applied on pre-swizzled global src + ds_read.
// Epilogue: fused bias + deterministic column partials + LDS-staged coalesced C.

#define LOAD_AQ(QH) \
  _Pragma("unroll") for (int mm = 0; mm < 4; ++mm) \
    _Pragma("unroll") for (int s = 0; s < 2; ++s) \
      aq[mm][s] = *(const bf16x8*)&lds[aoff + ((QH)*64 + mm*16 + fr)*64 + (((s*4 + fq) ^ w7) << 3)];

#define LOAD_BP(G) \
  _Pragma("unroll") for (int nn = 0; nn < 2; ++nn) \
    _Pragma("unroll") for (int s = 0; s < 2; ++s) \
      bq[(G)*2+nn][s] = *(const bf16x8*)&lds[boff + ((wc&1)*64 + ((G)*2+nn)*16 + fr)*64 + (((s*4 + fq) ^ w7) << 3)];

#define MFMA_QUAD(QH, G) \
  _Pragma("unroll") for (int mm = 0; mm < 4; ++mm) \
    _Pragma("unroll") for (int nn = 0; nn < 2; ++nn) \
      _Pragma("unroll") for (int s = 0; s < 2; ++s) \
        acc[(QH)*4+mm][(G)*2+nn] = __builtin_amdgcn_mfma_f32_16x16x32_bf16( \
            aq[mm][s], bq[(G)*2+nn][s], acc[(QH)*4+mm][(G)*2+nn], 0, 0, 0);

__global__ __launch_bounds__(512, 2) void gemm256(
    const unsigned short* __restrict__ A,
    const unsigned short* __restrict__ W,
    const float* __restrict__ bias,
    unsigned short* __restrict__ Y,
    float* __restrict__ psum, float* __restrict__ psumsq,
    int M, int N, int K, int rowBlkBase)
{
    __shared__ unsigned short lds[65536];   // [dbuf2][op2][half2][8192 elems] = 128 KiB

    const int nbx = N >> 8;
    const int nwg = gridDim.x;
    const int cpx = nwg >> 3;                        // nwg % 8 == 0 guaranteed
    const int bid = blockIdx.x;
    const int swzb = (bid & 7) * cpx + (bid >> 3);   // bijective XCD swizzle
    const int bm = swzb / nbx;
    const int bn = swzb % nbx;

    const int t    = threadIdx.x;
    const int wid  = t >> 6;
    const int lane = t & 63;
    const int wrh  = wid >> 2;        // row half (0/1): rows wrh*128..+127
    const int wc   = wid & 3;         // col quarter: cols wc*64..+63
    const int fr   = lane & 15;
    const int fq   = lane >> 4;
    const int w7   = fr & 7;

    // staging source map: thread t, load l in {0,1}: row = l*64 + (t>>3),
    // 16B slot = (t&7) ^ ((t>>3)&7)  (pre-swizzled so linear LDS == swizzled layout)
    const int r0s  = t >> 3;
    const int ce   = (((t & 7) ^ ((t >> 3) & 7)) << 3);   // col element

    const size_t baseA = (size_t)(bm << 8) * K;
    const size_t baseW = (size_t)(bn << 8) * K;
    const int NT = K >> 6;

    auto STAGE = [&](int b, int op, int h, int kt) {
        const unsigned short* gsrc = (op ? W : A)
            + (op ? baseW : baseA)
            + (size_t)((h << 7) + r0s) * K + (kt << 6) + ce;
        char* dst = (char*)lds + ((((b * 2 + op) * 2 + h) << 14) + (wid << 10));
        __builtin_amdgcn_global_load_lds((gbl_void_t*)gsrc, (lds_void_t*)dst, 16, 0, 0);
        __builtin_amdgcn_global_load_lds((gbl_void_t*)(gsrc + (size_t)64 * K),
                                         (lds_void_t*)(dst + 8192), 16, 0, 0);
    };

    f32x4 acc[8][4];
#pragma unroll
    for (int m = 0; m < 8; ++m)
#pragma unroll
        for (int n = 0; n < 4; ++n)
            acc[m][n] = (f32x4){0.f, 0.f, 0.f, 0.f};

    // ---- prologue: B(0), A(0), B(1); keep B(1) in flight ----
    STAGE(0, 1, 0, 0); STAGE(0, 1, 1, 0);
    STAGE(0, 0, 0, 0); STAGE(0, 0, 1, 0);
    if (NT > 1) { STAGE(1, 1, 0, 1); STAGE(1, 1, 1, 1); }
    asm volatile("s_waitcnt vmcnt(4)" ::: "memory");
    __builtin_amdgcn_s_barrier();

    bf16x8 aq[4][2], bq[4][2];

    for (int kt = 0; kt < NT; ++kt) {
        const int b = kt & 1;
        const unsigned aoff = (unsigned)(b * 4 + wrh) * 8192;
        const unsigned boff = (unsigned)(b * 4 + 2 + (wc >> 1)) * 8192;

        // ---- phase 0: A rows 0-3 + B cols 0-1; stage A0(kt+1) ----
        LOAD_AQ(0);
        LOAD_BP(0);
        if (kt + 1 < NT) STAGE(b ^ 1, 0, 0, kt + 1);
        asm volatile("s_waitcnt lgkmcnt(8)" ::: "memory");   // throttle 12-read phase
        __builtin_amdgcn_s_barrier();
        asm volatile("s_waitcnt lgkmcnt(0)" ::: "memory");
        __builtin_amdgcn_s_setprio(1);
        MFMA_QUAD(0, 0);
        __builtin_amdgcn_s_setprio(0);
        __builtin_amdgcn_s_barrier();

        // ---- phase 1: B cols 2-3; stage A1(kt+1) ----
        LOAD_BP(1);
        if (kt + 1 < NT) STAGE(b ^ 1, 0, 1, kt + 1);
        __builtin_amdgcn_s_barrier();
        asm volatile("s_waitcnt lgkmcnt(0)" ::: "memory");
        __builtin_amdgcn_s_setprio(1);
        MFMA_QUAD(0, 1);
        __builtin_amdgcn_s_setprio(0);
        __builtin_amdgcn_s_barrier();

        // ---- phase 2: A rows 4-7; stage B0(kt+2) ----
        LOAD_AQ(1);
        if (kt + 2 < NT) STAGE(b, 1, 0, kt + 2);
        __builtin_amdgcn_s_barrier();
        asm volatile("s_waitcnt lgkmcnt(0)" ::: "memory");
        __builtin_amdgcn_s_setprio(1);
        MFMA_QUAD(1, 0);
        __builtin_amdgcn_s_setprio(0);
        __builtin_amdgcn_s_barrier();

        // ---- phase 3: stage B1(kt+2); counted vmcnt; last quadrant ----
        if (kt + 2 < NT) {
            STAGE(b, 1, 1, kt + 2);
            asm volatile("s_waitcnt vmcnt(4)" ::: "memory");
        } else {
            asm volatile("s_waitcnt vmcnt(0)" ::: "memory");
        }
        __builtin_amdgcn_s_barrier();
        __builtin_amdgcn_s_setprio(1);
        MFMA_QUAD(1, 1);
        __builtin_amdgcn_s_setprio(0);
        __builtin_amdgcn_s_barrier();
    }

    // ---- epilogue: bias, deterministic column stats, LDS-staged coalesced C ----
    float bv[4];
#pragma unroll
    for (int nn = 0; nn < 4; ++nn) bv[nn] = bias[(bn << 8) + wc * 64 + nn * 16 + fr];

    // (1) column partial sums -> psum/psumsq (K-loop ended with a barrier)
    float* sSum = (float*)lds;             // [256 cols][8 slots]
    float* sSq  = (float*)lds + 256 * 8;   // [256 cols][8 slots]
#pragma unroll
    for (int nn = 0; nn < 4; ++nn) {
        float s = 0.f, q = 0.f;
#pragma unroll
        for (int mm = 0; mm < 8; ++mm)
#pragma unroll
            for (int r = 0; r < 4; ++r) {
                float v = acc[mm][nn][r] + bv[nn];
                s += v; q += v * v;
            }
        const int col = wc * 64 + nn * 16 + fr;
        const int sl  = wrh * 4 + fq;
        sSum[col * 8 + sl] = s;
        sSq [col * 8 + sl] = q;
    }
    __syncthreads();
    if (t < 256) {
        float s = 0.f, q = 0.f;
#pragma unroll
        for (int k = 0; k < 8; ++k) { s += sSum[t * 8 + k]; q += sSq[t * 8 + k]; }
        psum  [(size_t)(rowBlkBase + bm) * N + (bn << 8) + t] = s;
        psumsq[(size_t)(rowBlkBase + bm) * N + (bn << 8) + t] = q;
    }
    __syncthreads();

    // (2) stage C-tile bf16 into the (now dead) 128 KiB LDS: [256 rows][256 cols]
#pragma unroll
    for (int nn = 0; nn < 4; ++nn) {
        const int col = wc * 64 + nn * 16 + fr;
#pragma unroll
        for (int mm = 0; mm < 8; ++mm) {
            const int row0 = wrh * 128 + mm * 16 + fq * 4;
#pragma unroll
            for (int r = 0; r < 4; ++r)
                lds[(row0 + r) * 256 + col] = f2bf(acc[mm][nn][r] + bv[nn]);
        }
    }
    __syncthreads();

    // (3) coalesced write-out: 16 us8 (16B) stores per thread, 1 KiB per wave-op
    {
        const size_t outBase = (size_t)(bm << 8) * N + (bn << 8);
#pragma unroll
        for (int i = 0; i < 16; ++i) {
            const int u   = t + i * 512;        // us8 index within tile [0,8192)
            const int row = u >> 5, sl = u & 31;
            us8 v = *(const us8*)&lds[row * 256 + sl * 8];
            *(us8*)&Y[outBase + (size_t)row * N + sl * 8] = v;
        }
    }
}

// ---------------- BN stats finalize: reduce row-block partials -> scale/shift ----
__global__ __launch_bounds__(256) void col_stats2(
    const float* __restrict__ psum, const float* __restrict__ psumsq,
    const float* __restrict__ g, const float* __restrict__ be,
    float* __restrict__ scale, float* __restrict__ shift,
    int N, int NB, float invM)
{
    const int col = blockIdx.x * 256 + threadIdx.x;
    float s = 0.f, ss = 0.f;
    for (int c = 0; c < NB; ++c) {
        s  += psum  [(size_t)c * N + col];
        ss += psumsq[(size_t)c * N + col];
    }
    float mu  = s * invM;
    float var = ss * invM - mu * mu;   // biased var, matches torch BN normalization
    float a = g[col] * rsqrtf(var + 1e-5f);
    scale[col] = a;
    shift[col] = be[col] - mu * a;
}

// ---------------- fused normalize + LeakyReLU(0.5) copy (grid-stride) -------------
// src==dst is safe (pure elementwise).
__global__ __launch_bounds__(256) void norm_full(
    const unsigned short* __restrict__ src, unsigned short* __restrict__ dst,
    const float* __restrict__ scale, const float* __restrict__ shift,
    unsigned colMask8, size_t n8)
{
    const size_t stride = (size_t)gridDim.x * 256;
    for (size_t i = (size_t)blockIdx.x * 256 + threadIdx.x; i < n8; i += stride) {
        us8 v = *((const us8*)src + i);
        const unsigned c8 = (unsigned)i & colMask8;       // us8-granular column
        const float4* sc = (const float4*)scale + c8 * 2;
        const float4* sh = (const float4*)shift + c8 * 2;
        float4 s0 = sc[0], s1 = sc[1], h0 = sh[0], h1 = sh[1];
        float xs[8];
        xs[0] = bf2f(v[0]) * s0.x + h0.x;  xs[1] = bf2f(v[1]) * s0.y + h0.y;
        xs[2] = bf2f(v[2]) * s0.z + h0.z;  xs[3] = bf2f(v[3]) * s0.w + h0.w;
        xs[4] = bf2f(v[4]) * s1.x + h1.x;  xs[5] = bf2f(v[5]) * s1.y + h1.y;
        xs[6] = bf2f(v[6]) * s1.z + h1.z;  xs[7] = bf2f(v[7]) * s1.w + h1.w;
        us8 o;
#pragma unroll
        for (int j = 0; j < 8; ++j) {
            float x = xs[j];
            x = fmaxf(x, 0.5f * x);           // LeakyReLU(0.5) for any sign
            o[j] = f2bf(x);
        }
        *((us8*)dst + i) = o;
    }
}

// ---------------- final matvec with fused norm+leaky on X ----------------
__global__ __launch_bounds__(256) void matvec_norm_out(
    const unsigned short* __restrict__ X, const float* __restrict__ scale,
    const float* __restrict__ shift, const float* __restrict__ wvec,
    const float* __restrict__ bout, float* __restrict__ out, int Kd)
{
    const int row  = blockIdx.x * 4 + (threadIdx.x >> 6);
    const int lane = threadIdx.x & 63;
    const unsigned short* xr = X + (size_t)row * Kd;
    float s = 0.f;
    for (int j = lane * 8; j < Kd; j += 512) {
        us8 x = *(const us8*)(xr + j);
        const float4* sc = (const float4*)(scale + j);
        const float4* sh = (const float4*)(shift + j);
        const float4* wv = (const float4*)(wvec + j);
        float4 s0 = sc[0], s1 = sc[1], h0 = sh[0], h1 = sh[1];
        float4 w0 = wv[0], w1 = wv[1];
        float xs[8] = {
            bf2f(x[0]) * s0.x + h0.x, bf2f(x[1]) * s0.y + h0.y,
            bf2f(x[2]) * s0.z + h0.z, bf2f(x[3]) * s0.w + h0.w,
            bf2f(x[4]) * s1.x + h1.x, bf2f(x[5]) * s1.y + h1.y,
            bf2f(x[6]) * s1.z + h1.z, bf2f(x[7]) * s1.w + h1.w };
        float wf[8] = { w0.x, w0.y, w0.z, w0.w, w1.x, w1.y, w1.z, w1.w };
#pragma unroll
        for (int e = 0; e < 8; ++e) {
            float xv = xs[e];
            xv = fmaxf(xv, 0.5f * xv);
            s += xv * wf[e];
        }
    }
#pragma unroll
    for (int off = 32; off > 0; off >>= 1) s += __shfl_down(s, off);
    if (lane == 0) out[row] = s + bout[0];
}

extern "C" void kernel_launch(void* const* d_in, const int* in_sizes, int n_in,
                              void* d_out, int out_size, void* d_ws, size_t ws_size,
                              hipStream_t stream)
{
    const float* x    = (const float*)d_in[0];
    const float* w1   = (const float*)d_in[1];
    const float* b1   = (const float*)d_in[2];
    const float* g1   = (const float*)d_in[3];
    const float* be1  = (const float*)d_in[4];
    const float* w2   = (const float*)d_in[5];
    const float* b2   = (const float*)d_in[6];
    const float* g2   = (const float*)d_in[7];
    const float* be2  = (const float*)d_in[8];
    const float* w3   = (const float*)d_in[9];
    const float* b3   = (const float*)d_in[10];
    const float* g3   = (const float*)d_in[11];
    const float* be3  = (const float*)d_in[12];
    const float* wout = (const float*)d_in[13];
    const float* bout = (const float*)d_in[14];
    float* out = (float*)d_out;

    const int B = 32768, D = 512, H1 = 2048, H2 = 2048, H3 = 1024;
    const int NB = B / 256;             // 128 row-blocks of partial stats
    const int RCH = 8192;               // row chunk for in-place GEMM2 (4 chunks)
    const float invB = 1.0f / (float)B;
    char* ws = (char*)d_ws;

    // ---------- Plan C: bufA + dedicated Y3 + chunk scratch (~252 MB) ----------
    {
        size_t off = 0;
        auto alloc = [&](size_t bytes) -> char* {
            char* p = ws + off;
            off += (bytes + 255) & ~(size_t)255;
            return p;
        };
        unsigned short* bufA    = (unsigned short*)alloc((size_t)B * H1 * 2);   // 134.2 MB
        unsigned short* bufY3   = (unsigned short*)alloc((size_t)B * H3 * 2);   //  67.1 MB
        unsigned short* scratch = (unsigned short*)alloc((size_t)RCH * H1 * 2); //  33.6 MB
        unsigned short* W1b     = (unsigned short*)alloc((size_t)H1 * D * 2);   //   2.1 MB
        unsigned short* W2b     = (unsigned short*)alloc((size_t)H2 * H1 * 2);  //   8.4 MB
        unsigned short* W3b     = (unsigned short*)alloc((size_t)H3 * H2 * 2);  //   4.2 MB
        float* psum   = (float*)alloc((size_t)NB * H1 * 4);                     //   1.0 MB
        float* psumsq = (float*)alloc((size_t)NB * H1 * 4);                     //   1.0 MB
        float* scale  = (float*)alloc((size_t)H1 * 4);
        float* shift  = (float*)alloc((size_t)H1 * 4);

        if (off <= ws_size) {
            size_t n8;
            n8 = (size_t)B * D / 8;   cast_bf16<<<(unsigned)((n8 + 255) / 256), 256, 0, stream>>>(x,  scratch, n8);
            n8 = (size_t)H1 * D / 8;  cast_bf16<<<(unsigned)((n8 + 255) / 256), 256, 0, stream>>>(w1, W1b, n8);
            n8 = (size_t)H2 * H1 / 8; cast_bf16<<<(unsigned)((n8 + 255) / 256), 256, 0, stream>>>(w2, W2b, n8);
            n8 = (size_t)H3 * H2 / 8; cast_bf16<<<(unsigned)((n8 + 255) / 256), 256, 0, stream>>>(w3, W3b, n8);

            const size_t chunk8 = (size_t)RCH * H1 / 8;

            // layer 1: Xb @ W1^T -> bufA raw + stats
            gemm256<<<(B / 256) * (H1 / 256), 512, 0, stream>>>(
                scratch, W1b, b1, bufA, psum, psumsq, B, H1, D, 0);
            col_stats2<<<H1 / 256, 256, 0, stream>>>(psum, psumsq, g1, be1, scale, shift, H1, NB, invB);

            // layer 2: chunked in-place on bufA; norm(L1) fused into the chunk copy
            for (int c = 0; c < B / RCH; ++c) {
                norm_full<<<2048, 256, 0, stream>>>(
                    bufA + (size_t)c * RCH * H1, scratch, scale, shift, H1 / 8 - 1, chunk8);
                gemm256<<<(RCH / 256) * (H2 / 256), 512, 0, stream>>>(
                    scratch, W2b, b2, bufA + (size_t)c * RCH * H1, psum, psumsq,
                    RCH, H2, H1, c * (RCH / 256));
            }
            col_stats2<<<H2 / 256, 256, 0, stream>>>(psum, psumsq, g2, be2, scale, shift, H2, NB, invB);

            // norm(L2) in place over the whole buffer, then layer 3 as ONE dispatch
            norm_full<<<4096, 256, 0, stream>>>(bufA, bufA, scale, shift, H2 / 8 - 1, (size_t)B * H2 / 8);
            gemm256<<<(B / 256) * (H3 / 256), 512, 0, stream>>>(
                bufA, W3b, b3, bufY3, psum, psumsq, B, H3, H2, 0);
            col_stats2<<<H3 / 256, 256, 0, stream>>>(psum, psumsq, g3, be3, scale, shift, H3, NB, invB);

            // output: norm(L3) fused into the matvec
            matvec_norm_out<<<B / 4, 256, 0, stream>>>(bufY3, scale, shift, wout, bout, out, H3);
            return;
        }
    }

    // ---------- Plan B fallback: fully chunked in-place (~185 MB) ----------
    {
        size_t off = 0;
        auto alloc = [&](size_t bytes) -> char* {
            char* p = ws + off;
            off += (bytes + 255) & ~(size_t)255;
            return p;
        };
        unsigned short* bufA    = (unsigned short*)alloc((size_t)B * H1 * 2);
        unsigned short* scratch = (unsigned short*)alloc((size_t)RCH * H1 * 2);
        unsigned short* W1b     = (unsigned short*)alloc((size_t)H1 * D * 2);
        unsigned short* W2b     = (unsigned short*)alloc((size_t)H2 * H1 * 2);
        unsigned short* W3b     = (unsigned short*)alloc((size_t)H3 * H2 * 2);
        float* psum   = (float*)alloc((size_t)NB * H1 * 4);
        float* psumsq = (float*)alloc((size_t)NB * H1 * 4);
        float* scale  = (float*)alloc((size_t)H1 * 4);
        float* shift  = (float*)alloc((size_t)H1 * 4);

        if (off > ws_size) {            // even fallback doesn't fit: report ws_size
            report_ws<<<1, 1, 0, stream>>>(out, (float)ws_size);
            return;
        }

        size_t n8;
        n8 = (size_t)B * D / 8;   cast_bf16<<<(unsigned)((n8 + 255) / 256), 256, 0, stream>>>(x,  scratch, n8);
        n8 = (size_t)H1 * D / 8;  cast_bf16<<<(unsigned)((n8 + 255) / 256), 256, 0, stream>>>(w1, W1b, n8);
        n8 = (size_t)H2 * H1 / 8; cast_bf16<<<(unsigned)((n8 + 255) / 256), 256, 0, stream>>>(w2, W2b, n8);
        n8 = (size_t)H3 * H2 / 8; cast_bf16<<<(unsigned)((n8 + 255) / 256), 256, 0, stream>>>(w3, W3b, n8);

        const size_t chunk8 = (size_t)RCH * H1 / 8;

        gemm256<<<(B / 256) * (H1 / 256), 512, 0, stream>>>(
            scratch, W1b, b1, bufA, psum, psumsq, B, H1, D, 0);
        col_stats2<<<H1 / 256, 256, 0, stream>>>(psum, psumsq, g1, be1, scale, shift, H1, NB, invB);

        for (int c = 0; c < B / RCH; ++c) {
            norm_full<<<2048, 256, 0, stream>>>(
                bufA + (size_t)c * RCH * H1, scratch, scale, shift, H1 / 8 - 1, chunk8);
            gemm256<<<(RCH / 256) * (H2 / 256), 512, 0, stream>>>(
                scratch, W2b, b2, bufA + (size_t)c * RCH * H1, psum, psumsq,
                RCH, H2, H1, c * (RCH / 256));
        }
        col_stats2<<<H2 / 256, 256, 0, stream>>>(psum, psumsq, g2, be2, scale, shift, H2, NB, invB);

        for (int c = 0; c < B / RCH; ++c) {
            norm_full<<<2048, 256, 0, stream>>>(
                bufA + (size_t)c * RCH * H2, scratch, scale, shift, H2 / 8 - 1, chunk8);
            gemm256<<<(RCH / 256) * (H3 / 256), 512, 0, stream>>>(
                scratch, W3b, b3, bufA + (size_t)c * RCH * H3, psum, psumsq,
                RCH, H3, H2, c * (RCH / 256));
        }
        col_stats2<<<H3 / 256, 256, 0, stream>>>(psum, psumsq, g3, be3, scale, shift, H3, NB, invB);

        matvec_norm_out<<<B / 4, 256, 0, stream>>>(bufA, scale, shift, wout, bout, out, H3);
    }
}

// Round 9
// 673.055 us; speedup vs baseline: 2.5942x; 1.0137x over previous
//
#include <hip/hip_runtime.h>

typedef __bf16 bf16x8 __attribute__((ext_vector_type(8)));
typedef float f32x4 __attribute__((ext_vector_type(4)));
typedef unsigned short us8 __attribute__((ext_vector_type(8)));

typedef __attribute__((address_space(3))) void lds_void_t;
typedef const __attribute__((address_space(1))) void gbl_void_t;

__device__ __forceinline__ unsigned short f2bf(float f) {
    unsigned u = __builtin_bit_cast(unsigned, f);
    u += 0x7FFFu + ((u >> 16) & 1u);   // round-to-nearest-even
    return (unsigned short)(u >> 16);
}
__device__ __forceinline__ float bf2f(unsigned short h) {
    unsigned u = ((unsigned)h) << 16;
    return __builtin_bit_cast(float, u);
}

// ---------------- diagnostic: reveal ws_size via absmax if workspace too small ----
__global__ void report_ws(float* out, float v) { out[0] = v; }

// ---------------- f32 -> bf16 cast (vectorized) ----------------
__global__ __launch_bounds__(256) void cast_bf16(
    const float* __restrict__ src, unsigned short* __restrict__ dst, size_t n8)
{
    size_t i = (size_t)blockIdx.x * 256 + threadIdx.x;
    if (i >= n8) return;
    const float4* s = (const float4*)src + i * 2;
    float4 a = s[0], b = s[1];
    us8 o;
    o[0] = f2bf(a.x); o[1] = f2bf(a.y); o[2] = f2bf(a.z); o[3] = f2bf(a.w);
    o[4] = f2bf(b.x); o[5] = f2bf(b.y); o[6] = f2bf(b.z); o[7] = f2bf(b.w);
    *((us8*)dst + i) = o;
}

// ================= 256x256 8-phase bf16 GEMM (T2+T3+T4+T5) =================
// Y = A @ W^T + bias;  A [M,K], W [N,K] bf16 row-major, Y [M,N] bf16.
// 512 threads = 8 waves. BK=64, dbuf LDS 128 KiB (+16 KiB norm table).
// NORMA=1: A is reg-staged with fused y = leaky(nsc[k]*a + nsh[k]) (K<=2048).
//   A-loads issued ph0; transform+ds_write in ph3 after MFMA(1,1). The compiler's
//   wait on A-regs (issued AFTER B(kt+1) in the vmcnt queue) drains B(kt+1) too.
// Epilogue: fused bias + deterministic column partials + LDS-staged coalesced C.

#define LOAD_AQ(QH) \
  _Pragma("unroll") for (int mm = 0; mm < 4; ++mm) \
    _Pragma("unroll") for (int s = 0; s < 2; ++s) \
      aq[mm][s] = *(const bf16x8*)&lds[aoff + ((QH)*64 + mm*16 + fr)*64 + (((s*4 + fq) ^ w7) << 3)];

#define LOAD_BP(G) \
  _Pragma("unroll") for (int nn = 0; nn < 2; ++nn) \
    _Pragma("unroll") for (int s = 0; s < 2; ++s) \
      bq[(G)*2+nn][s] = *(const bf16x8*)&lds[boff + ((wc&1)*64 + ((G)*2+nn)*16 + fr)*64 + (((s*4 + fq) ^ w7) << 3)];

#define MFMA_QUAD(QH, G) \
  _Pragma("unroll") for (int mm = 0; mm < 4; ++mm) \
    _Pragma("unroll") for (int nn = 0; nn < 2; ++nn) \
      _Pragma("unroll") for (int s = 0; s < 2; ++s) \
        acc[(QH)*4+mm][(G)*2+nn] = __builtin_amdgcn_mfma_f32_16x16x32_bf16( \
            aq[mm][s], bq[(G)*2+nn][s], acc[(QH)*4+mm][(G)*2+nn], 0, 0, 0);

template<bool NORMA>
__global__ __launch_bounds__(512, 2) void gemm256(
    const unsigned short* __restrict__ A,
    const unsigned short* __restrict__ W,
    const float* __restrict__ bias,
    unsigned short* __restrict__ Y,
    float* __restrict__ psum, float* __restrict__ psumsq,
    int M, int N, int K, int rowBlkBase,
    const float* __restrict__ nsc, const float* __restrict__ nsh)
{
    __shared__ unsigned short lds[65536];   // [dbuf2][op2][half2][8192 elems] = 128 KiB
    __shared__ float ntab[4096];            // [scale 2048][shift 2048] (NORMA only)

    const int nbx = N >> 8;
    const int nwg = gridDim.x;
    const int cpx = nwg >> 3;                        // nwg % 8 == 0 guaranteed
    const int bid = blockIdx.x;
    const int swzb = (bid & 7) * cpx + (bid >> 3);   // bijective XCD swizzle
    const int bm = swzb / nbx;
    const int bn = swzb % nbx;

    const int t    = threadIdx.x;
    const int wid  = t >> 6;
    const int lane = t & 63;
    const int wrh  = wid >> 2;        // row half (0/1)
    const int wc   = wid & 3;         // col quarter
    const int fr   = lane & 15;
    const int fq   = lane >> 4;
    const int w7   = fr & 7;

    const int r0s  = t >> 3;                              // staging row 0..63
    const int ce   = (((t & 7) ^ ((t >> 3) & 7)) << 3);   // pre-swizzled col elem

    const size_t baseA = (size_t)(bm << 8) * K;
    const size_t baseW = (size_t)(bn << 8) * K;
    const int NT = K >> 6;

    auto STAGE = [&](int b, int op, int h, int kt) {
        const unsigned short* gsrc = (op ? W : A)
            + (op ? baseW : baseA)
            + (size_t)((h << 7) + r0s) * K + (kt << 6) + ce;
        char* dst = (char*)lds + ((((b * 2 + op) * 2 + h) << 14) + (wid << 10));
        __builtin_amdgcn_global_load_lds((gbl_void_t*)gsrc, (lds_void_t*)dst, 16, 0, 0);
        __builtin_amdgcn_global_load_lds((gbl_void_t*)(gsrc + (size_t)64 * K),
                                         (lds_void_t*)(dst + 8192), 16, 0, 0);
    };

    us8 av[4];   // NORMA: in-flight A (rows r0s+{0,64,128,192})
    auto ALOAD = [&](int kt) {
        const unsigned short* a0 = A + baseA + (size_t)(kt << 6) + ce;
        av[0] = *(const us8*)(a0 + (size_t)(r0s)       * K);
        av[1] = *(const us8*)(a0 + (size_t)(r0s + 64)  * K);
        av[2] = *(const us8*)(a0 + (size_t)(r0s + 128) * K);
        av[3] = *(const us8*)(a0 + (size_t)(r0s + 192) * K);
    };
    auto XFORM = [&](int bdst, int kt) {   // transform av -> LDS buf bdst A-region
        const int cb = (kt << 6) + ce;
        float4 s0 = *(const float4*)&ntab[cb];
        float4 s1 = *(const float4*)&ntab[cb + 4];
        float4 h0 = *(const float4*)&ntab[2048 + cb];
        float4 h1 = *(const float4*)&ntab[2048 + cb + 4];
        float scv[8] = {s0.x,s0.y,s0.z,s0.w,s1.x,s1.y,s1.z,s1.w};
        float shv[8] = {h0.x,h0.y,h0.z,h0.w,h1.x,h1.y,h1.z,h1.w};
#pragma unroll
        for (int q = 0; q < 4; ++q) {
            us8 o;
#pragma unroll
            for (int e = 0; e < 8; ++e) {
                float f = bf2f(av[q][e]);
                float y = f * scv[e] + shv[e];
                y = fmaxf(y, 0.5f * y);          // LeakyReLU(0.5), matches norm_full
                o[e] = f2bf(y);
            }
            const int h = q >> 1, l = q & 1;
            *(us8*)&lds[((unsigned)(bdst * 4 + h) << 13) + l * 4096 + t * 8] = o;
        }
    };

    f32x4 acc[8][4];
#pragma unroll
    for (int m = 0; m < 8; ++m)
#pragma unroll
        for (int n = 0; n < 4; ++n)
            acc[m][n] = (f32x4){0.f, 0.f, 0.f, 0.f};

    // ---- prologue ----
    if constexpr (NORMA) {
        ((float4*)ntab)[t]       = ((const float4*)nsc)[t];   // 2048 scale
        ((float4*)ntab)[512 + t] = ((const float4*)nsh)[t];   // 2048 shift
    }
    STAGE(0, 1, 0, 0); STAGE(0, 1, 1, 0);                 // B(0)
    if constexpr (!NORMA) { STAGE(0, 0, 0, 0); STAGE(0, 0, 1, 0); }
    else                  { ALOAD(0); }
    if (NT > 1) { STAGE(1, 1, 0, 1); STAGE(1, 1, 1, 1); } // B(1), stays in flight
    if constexpr (NORMA) {
        __syncthreads();                                   // ntab visible
        XFORM(0, 0);                                       // (waits av; drains B(0) too)
        asm volatile("s_waitcnt lgkmcnt(0)" ::: "memory");
    } else {
        asm volatile("s_waitcnt vmcnt(4)" ::: "memory");
    }
    __builtin_amdgcn_s_barrier();

    bf16x8 aq[4][2], bq[4][2];

    for (int kt = 0; kt < NT; ++kt) {
        const int b = kt & 1;
        const unsigned aoff = (unsigned)(b * 4 + wrh) * 8192;
        const unsigned boff = (unsigned)(b * 4 + 2 + (wc >> 1)) * 8192;

        // ---- phase 0: A rows 0-3 + B cols 0-1; issue next A ----
        LOAD_AQ(0);
        LOAD_BP(0);
        if (kt + 1 < NT) {
            if constexpr (NORMA) { ALOAD(kt + 1); __builtin_amdgcn_sched_barrier(0); }
            else                 { STAGE(b ^ 1, 0, 0, kt + 1); }
        }
        asm volatile("s_waitcnt lgkmcnt(8)" ::: "memory");
        __builtin_amdgcn_s_barrier();
        asm volatile("s_waitcnt lgkmcnt(0)" ::: "memory");
        __builtin_amdgcn_s_setprio(1);
        MFMA_QUAD(0, 0);
        __builtin_amdgcn_s_setprio(0);
        __builtin_amdgcn_s_barrier();

        // ---- phase 1: B cols 2-3 ----
        LOAD_BP(1);
        if constexpr (!NORMA) { if (kt + 1 < NT) STAGE(b ^ 1, 0, 1, kt + 1); }
        __builtin_amdgcn_s_barrier();
        asm volatile("s_waitcnt lgkmcnt(0)" ::: "memory");
        __builtin_amdgcn_s_setprio(1);
        MFMA_QUAD(0, 1);
        __builtin_amdgcn_s_setprio(0);
        __builtin_amdgcn_s_barrier();

        // ---- phase 2: A rows 4-7; stage B0(kt+2) ----
        LOAD_AQ(1);
        if (kt + 2 < NT) STAGE(b, 1, 0, kt + 2);
        __builtin_amdgcn_s_barrier();
        asm volatile("s_waitcnt lgkmcnt(0)" ::: "memory");
        __builtin_amdgcn_s_setprio(1);
        MFMA_QUAD(1, 0);
        __builtin_amdgcn_s_setprio(0);
        __builtin_amdgcn_s_barrier();

        // ---- phase 3: stage B1(kt+2); MFMA; A transform/write (NORMA) ----
        if (kt + 2 < NT) STAGE(b, 1, 1, kt + 2);
        if constexpr (NORMA) {
            __builtin_amdgcn_s_setprio(1);
            MFMA_QUAD(1, 1);
            __builtin_amdgcn_s_setprio(0);
            if (kt + 1 < NT) XFORM(b ^ 1, kt + 1);   // implicit vmcnt wait drains B(kt+1)
            asm volatile("s_waitcnt lgkmcnt(0)" ::: "memory");
            __builtin_amdgcn_s_barrier();
        } else {
            if (kt + 2 < NT) { asm volatile("s_waitcnt vmcnt(4)" ::: "memory"); }
            else             { asm volatile("s_waitcnt vmcnt(0)" ::: "memory"); }
            __builtin_amdgcn_s_barrier();
            __builtin_amdgcn_s_setprio(1);
            MFMA_QUAD(1, 1);
            __builtin_amdgcn_s_setprio(0);
            __builtin_amdgcn_s_barrier();
        }
    }

    // ---- epilogue: bias, deterministic column stats, LDS-staged coalesced C ----
    float bv[4];
#pragma unroll
    for (int nn = 0; nn < 4; ++nn) bv[nn] = bias[(bn << 8) + wc * 64 + nn * 16 + fr];

    float* sSum = (float*)lds;             // [256 cols][8 slots]
    float* sSq  = (float*)lds + 256 * 8;
#pragma unroll
    for (int nn = 0; nn < 4; ++nn) {
        float s = 0.f, q = 0.f;
#pragma unroll
        for (int mm = 0; mm < 8; ++mm)
#pragma unroll
            for (int r = 0; r < 4; ++r) {
                float v = acc[mm][nn][r] + bv[nn];
                s += v; q += v * v;
            }
        const int col = wc * 64 + nn * 16 + fr;
        const int sl  = wrh * 4 + fq;
        sSum[col * 8 + sl] = s;
        sSq [col * 8 + sl] = q;
    }
    __syncthreads();
    if (t < 256) {
        float s = 0.f, q = 0.f;
#pragma unroll
        for (int k = 0; k < 8; ++k) { s += sSum[t * 8 + k]; q += sSq[t * 8 + k]; }
        psum  [(size_t)(rowBlkBase + bm) * N + (bn << 8) + t] = s;
        psumsq[(size_t)(rowBlkBase + bm) * N + (bn << 8) + t] = q;
    }
    __syncthreads();

    // stage C bf16 into dead LDS [256][256], then coalesced us8 write-out
#pragma unroll
    for (int nn = 0; nn < 4; ++nn) {
        const int col = wc * 64 + nn * 16 + fr;
#pragma unroll
        for (int mm = 0; mm < 8; ++mm) {
            const int row0 = wrh * 128 + mm * 16 + fq * 4;
#pragma unroll
            for (int r = 0; r < 4; ++r)
                lds[(row0 + r) * 256 + col] = f2bf(acc[mm][nn][r] + bv[nn]);
        }
    }
    __syncthreads();
    {
        const size_t outBase = (size_t)(bm << 8) * N + (bn << 8);
#pragma unroll
        for (int i = 0; i < 16; ++i) {
            const int u   = t + i * 512;
            const int row = u >> 5, sl = u & 31;
            us8 v = *(const us8*)&lds[row * 256 + sl * 8];
            *(us8*)&Y[outBase + (size_t)row * N + sl * 8] = v;
        }
    }
}

// ---------------- BN stats finalize: reduce row-block partials -> scale/shift ----
__global__ __launch_bounds__(256) void col_stats2(
    const float* __restrict__ psum, const float* __restrict__ psumsq,
    const float* __restrict__ g, const float* __restrict__ be,
    float* __restrict__ scale, float* __restrict__ shift,
    int N, int NB, float invM)
{
    const int col = blockIdx.x * 256 + threadIdx.x;
    float s = 0.f, ss = 0.f;
    for (int c = 0; c < NB; ++c) {
        s  += psum  [(size_t)c * N + col];
        ss += psumsq[(size_t)c * N + col];
    }
    float mu  = s * invM;
    float var = ss * invM - mu * mu;
    float a = g[col] * rsqrtf(var + 1e-5f);
    scale[col] = a;
    shift[col] = be[col] - mu * a;
}

// ---------------- fused normalize + LeakyReLU(0.5) copy (grid-stride) -------------
__global__ __launch_bounds__(256) void norm_full(
    const unsigned short* __restrict__ src, unsigned short* __restrict__ dst,
    const float* __restrict__ scale, const float* __restrict__ shift,
    unsigned colMask8, size_t n8)
{
    const size_t stride = (size_t)gridDim.x * 256;
    for (size_t i = (size_t)blockIdx.x * 256 + threadIdx.x; i < n8; i += stride) {
        us8 v = *((const us8*)src + i);
        const unsigned c8 = (unsigned)i & colMask8;
        const float4* sc = (const float4*)scale + c8 * 2;
        const float4* sh = (const float4*)shift + c8 * 2;
        float4 s0 = sc[0], s1 = sc[1], h0 = sh[0], h1 = sh[1];
        float xs[8];
        xs[0] = bf2f(v[0]) * s0.x + h0.x;  xs[1] = bf2f(v[1]) * s0.y + h0.y;
        xs[2] = bf2f(v[2]) * s0.z + h0.z;  xs[3] = bf2f(v[3]) * s0.w + h0.w;
        xs[4] = bf2f(v[4]) * s1.x + h1.x;  xs[5] = bf2f(v[5]) * s1.y + h1.y;
        xs[6] = bf2f(v[6]) * s1.z + h1.z;  xs[7] = bf2f(v[7]) * s1.w + h1.w;
        us8 o;
#pragma unroll
        for (int j = 0; j < 8; ++j) {
            float x = xs[j];
            x = fmaxf(x, 0.5f * x);
            o[j] = f2bf(x);
        }
        *((us8*)dst + i) = o;
    }
}

// ---------------- final matvec with fused norm+leaky on X ----------------
__global__ __launch_bounds__(256) void matvec_norm_out(
    const unsigned short* __restrict__ X, const float* __restrict__ scale,
    const float* __restrict__ shift, const float* __restrict__ wvec,
    const float* __restrict__ bout, float* __restrict__ out, int Kd)
{
    const int row  = blockIdx.x * 4 + (threadIdx.x >> 6);
    const int lane = threadIdx.x & 63;
    const unsigned short* xr = X + (size_t)row * Kd;
    float s = 0.f;
    for (int j = lane * 8; j < Kd; j += 512) {
        us8 x = *(const us8*)(xr + j);
        const float4* sc = (const float4*)(scale + j);
        const float4* sh = (const float4*)(shift + j);
        const float4* wv = (const float4*)(wvec + j);
        float4 s0 = sc[0], s1 = sc[1], h0 = sh[0], h1 = sh[1];
        float4 w0 = wv[0], w1 = wv[1];
        float xs[8] = {
            bf2f(x[0]) * s0.x + h0.x, bf2f(x[1]) * s0.y + h0.y,
            bf2f(x[2]) * s0.z + h0.z, bf2f(x[3]) * s0.w + h0.w,
            bf2f(x[4]) * s1.x + h1.x, bf2f(x[5]) * s1.y + h1.y,
            bf2f(x[6]) * s1.z + h1.z, bf2f(x[7]) * s1.w + h1.w };
        float wf[8] = { w0.x, w0.y, w0.z, w0.w, w1.x, w1.y, w1.z, w1.w };
#pragma unroll
        for (int e = 0; e < 8; ++e) {
            float xv = xs[e];
            xv = fmaxf(xv, 0.5f * xv);
            s += xv * wf[e];
        }
    }
#pragma unroll
    for (int off = 32; off > 0; off >>= 1) s += __shfl_down(s, off);
    if (lane == 0) out[row] = s + bout[0];
}

extern "C" void kernel_launch(void* const* d_in, const int* in_sizes, int n_in,
                              void* d_out, int out_size, void* d_ws, size_t ws_size,
                              hipStream_t stream)
{
    const float* x    = (const float*)d_in[0];
    const float* w1   = (const float*)d_in[1];
    const float* b1   = (const float*)d_in[2];
    const float* g1   = (const float*)d_in[3];
    const float* be1  = (const float*)d_in[4];
    const float* w2   = (const float*)d_in[5];
    const float* b2   = (const float*)d_in[6];
    const float* g2   = (const float*)d_in[7];
    const float* be2  = (const float*)d_in[8];
    const float* w3   = (const float*)d_in[9];
    const float* b3   = (const float*)d_in[10];
    const float* g3   = (const float*)d_in[11];
    const float* be3  = (const float*)d_in[12];
    const float* wout = (const float*)d_in[13];
    const float* bout = (const float*)d_in[14];
    float* out = (float*)d_out;

    const int B = 32768, D = 512, H1 = 2048, H2 = 2048, H3 = 1024;
    const int NB = B / 256;             // 128 row-blocks of partial stats
    const int RCH = 16384;              // row chunk for in-place GEMM2 (2 chunks)
    const float invB = 1.0f / (float)B;
    char* ws = (char*)d_ws;

    size_t off = 0;
    auto alloc = [&](size_t bytes) -> char* {
        char* p = ws + off;
        off += (bytes + 255) & ~(size_t)255;
        return p;
    };
    unsigned short* bufA  = (unsigned short*)alloc((size_t)B * H1 * 2);   // 134.2 MB
    unsigned short* bufY3 = (unsigned short*)alloc((size_t)B * H3 * 2);   //  67.1 MB (Xb / GEMM2 scratch / Y3)
    unsigned short* W1b   = (unsigned short*)alloc((size_t)H1 * D * 2);   //   2.1 MB
    unsigned short* W2b   = (unsigned short*)alloc((size_t)H2 * H1 * 2);  //   8.4 MB
    unsigned short* W3b   = (unsigned short*)alloc((size_t)H3 * H2 * 2);  //   4.2 MB
    float* psum   = (float*)alloc((size_t)NB * H1 * 4);                   //   1.0 MB
    float* psumsq = (float*)alloc((size_t)NB * H1 * 4);                   //   1.0 MB
    float* scale  = (float*)alloc((size_t)H1 * 4);
    float* shift  = (float*)alloc((size_t)H1 * 4);

    if (off > ws_size) {                // ~218 MB; known to fit (round-8 Plan C ran)
        report_ws<<<1, 1, 0, stream>>>(out, (float)ws_size);
        return;
    }

    // --- input casts to bf16 (x lives at the head of bufY3 until GEMM1 consumes it) ---
    {
        size_t n8;
        n8 = (size_t)B * D / 8;   cast_bf16<<<(unsigned)((n8 + 255) / 256), 256, 0, stream>>>(x,  bufY3, n8);
        n8 = (size_t)H1 * D / 8;  cast_bf16<<<(unsigned)((n8 + 255) / 256), 256, 0, stream>>>(w1, W1b, n8);
        n8 = (size_t)H2 * H1 / 8; cast_bf16<<<(unsigned)((n8 + 255) / 256), 256, 0, stream>>>(w2, W2b, n8);
        n8 = (size_t)H3 * H2 / 8; cast_bf16<<<(unsigned)((n8 + 255) / 256), 256, 0, stream>>>(w3, W3b, n8);
    }

    // --- layer 1: Xb @ W1^T -> bufA raw + stats ---
    gemm256<false><<<(B / 256) * (H1 / 256), 512, 0, stream>>>(
        bufY3, W1b, b1, bufA, psum, psumsq, B, H1, D, 0, nullptr, nullptr);
    col_stats2<<<H1 / 256, 256, 0, stream>>>(psum, psumsq, g1, be1, scale, shift, H1, NB, invB);

    // --- layer 2: 2 chunks in place on bufA; norm(L1) fused into the chunk copy ---
    const size_t chunk8 = (size_t)RCH * H1 / 8;
    for (int c = 0; c < B / RCH; ++c) {
        norm_full<<<2048, 256, 0, stream>>>(
            bufA + (size_t)c * RCH * H1, bufY3, scale, shift, H1 / 8 - 1, chunk8);
        gemm256<false><<<(RCH / 256) * (H2 / 256), 512, 0, stream>>>(
            bufY3, W2b, b2, bufA + (size_t)c * RCH * H1, psum, psumsq,
            RCH, H2, H1, c * (RCH / 256), nullptr, nullptr);
    }
    col_stats2<<<H2 / 256, 256, 0, stream>>>(psum, psumsq, g2, be2, scale, shift, H2, NB, invB);

    // --- layer 3: ONE dispatch, norm(L2)+leaky fused into A-staging (NORMA) ---
    gemm256<true><<<(B / 256) * (H3 / 256), 512, 0, stream>>>(
        bufA, W3b, b3, bufY3, psum, psumsq, B, H3, H2, 0, scale, shift);
    col_stats2<<<H3 / 256, 256, 0, stream>>>(psum, psumsq, g3, be3, scale, shift, H3, NB, invB);

    // --- output: norm(L3) fused into the matvec ---
    matvec_norm_out<<<B / 4, 256, 0, stream>>>(bufY3, scale, shift, wout, bout, out, H3);
}